// Round 8
// baseline (301.908 us; speedup 1.0000x reference)
//
#include <hip/hip_runtime.h>
#include <hip/hip_bf16.h>
#include <math.h>

typedef __attribute__((ext_vector_type(8))) short bf16x8;
typedef __attribute__((ext_vector_type(4))) float f32x4;

#define MROWS 12544      // (128+128)*49
#define CDIM 768
#define INNER 96
#define S49 49
#define NSIDE 6272       // 128*49 rows per side
#define SCALE 0.10206207261596577f
// SCALE * log2(e): Q prescale so attn can use exp2 directly
#define SCALE_EXP2 ((float)(0.10206207261596577 * 1.4426950408889634))

__device__ __forceinline__ unsigned short f2bf(float f) {
  union { float f; unsigned u; } v; v.f = f;
  unsigned u = v.u;
  return (unsigned short)((u + 0x7fffu + ((u >> 16) & 1u)) >> 16);
}
__device__ __forceinline__ float bf2f(unsigned short h) {
  union { unsigned u; float f; } v; v.u = ((unsigned)h) << 16;
  return v.f;
}
// pack two floats to bf16x2 (round-to-nearest-ish): low=a, high=b
__device__ __forceinline__ unsigned pack_bf16_rn(float a, float b) {
  union { float f; unsigned u; } ua, ub; ua.f = a; ub.f = b;
  return __builtin_amdgcn_perm(ub.u + 0x8000u, ua.u + 0x8000u, 0x07060302u);
}

// async global->LDS, 16B per lane. Dest must be wave-uniform base + lane*16.
__device__ __forceinline__ void gld16(const unsigned short* g, unsigned short* l) {
  __builtin_amdgcn_global_load_lds(
      (const __attribute__((address_space(1))) unsigned int*)(g),
      (__attribute__((address_space(3))) unsigned int*)(l), 16, 0, 0);
}

// ---------------------------------------------------------------------------
// prep_all: one kernel, three phases by block range.
// ---------------------------------------------------------------------------
__global__ __launch_bounds__(256) void prep_all(
    const float* __restrict__ fa, const float* __restrict__ fb,
    const float* __restrict__ w10, const float* __restrict__ w11,
    const float* __restrict__ w12, const float* __restrict__ w20,
    const float* __restrict__ w21, const float* __restrict__ w22,
    unsigned short* __restrict__ X,
    unsigned short* __restrict__ W1T, unsigned short* __restrict__ W2T,
    unsigned short* __restrict__ VtKpad) {
  const int t = threadIdx.x;
  int id = blockIdx.x;
  if (id < 3072) {
    __shared__ float T[64][50];
    const int z = id / 1536; id -= z * 1536;
    const int ct = id % 12, img = id / 12;
    const float* feat = z ? fb : fa;
    const float* src = feat + (size_t)img * (CDIM * S49) + (size_t)ct * 64 * S49;
    for (int idx = t; idx < 64 * S49; idx += 256) {
      int cc = idx / S49, s = idx - cc * S49;
      T[cc][s] = src[cc * S49 + s];
    }
    __syncthreads();
    unsigned short* dst = X + (size_t)(z * 128 + img) * S49 * CDIM + ct * 64;
    for (int idx = t; idx < S49 * 64; idx += 256) {
      int s = idx >> 6, cc = idx & 63;
      dst[(size_t)s * CDIM + cc] = f2bf(T[cc][s]);
    }
  } else if (id < 5016) {
    __shared__ float T[32][33];
    id -= 3072;
    const float* src;
    unsigned short* dst;
    int C, ctile, rtile;
    if (id < 1728) {
      int wdx = id / 576, tid = id - wdx * 576;
      ctile = tid % 24; rtile = tid / 24;
      src = wdx == 0 ? w10 : (wdx == 1 ? w11 : w12);
      dst = W1T + (size_t)wdx * CDIM * CDIM;
      C = CDIM;
    } else {
      id -= 1728;
      int wdx = id / 72, tid = id - wdx * 72;
      ctile = tid % 3; rtile = tid / 3;
      src = wdx == 0 ? w20 : (wdx == 1 ? w21 : w22);
      dst = W2T + (size_t)wdx * INNER * CDIM;
      C = INNER;
    }
    const int c0 = ctile * 32, r0 = rtile * 32;
    for (int idx = t; idx < 1024; idx += 256) {
      int rr = idx >> 5, cc = idx & 31;
      T[rr][cc] = src[(size_t)(r0 + rr) * C + c0 + cc];
    }
    __syncthreads();
    for (int idx = t; idx < 1024; idx += 256) {
      int rr = idx >> 5, cc = idx & 31;
      dst[(size_t)(c0 + rr) * CDIM + r0 + cc] = f2bf(T[cc][rr]);
    }
  } else {
    id -= 5016;
    ushort4* p4 = (ushort4*)VtKpad;
    const ushort4 z = make_ushort4(0, 0, 0, 0);
#pragma unroll
    for (int i = 0; i < 32; i++)
      p4[(size_t)id * 8192 + i * 256 + t] = z;
  }
}

// ---------------------------------------------------------------------------
// gemm1b4: H[wdx] = relu(X @ W1[wdx]). 128x128 tile, BK=64, gld16 staging.
// Bijective XCD-chunked swizzle (T1/m204): verified WIN in R7 (+10us).
// ---------------------------------------------------------------------------
__global__ __launch_bounds__(512) void gemm1b4(const unsigned short* __restrict__ X,
                                               const unsigned short* __restrict__ W1T,
                                               unsigned short* __restrict__ H,
                                               int wbase, int hsel) {
  __shared__ __align__(16) unsigned short As[128 * 64];
  __shared__ __align__(16) unsigned short Bs[128 * 64];
  const int t = threadIdx.x;
  const int lane = t & 63, w = t >> 6;
  const int lr = lane & 15, lq = lane >> 4;
  const int wm = w & 3;          // m quarter (32 rows)
  const int wn = w >> 2;         // n half (64 cols)
  // ---- bijective XCD swizzle over the full grid (m204 formula)
  const int gx = gridDim.x, gxy = gx * gridDim.y;
  const int nwg = gxy * gridDim.z;
  const int orig = blockIdx.x + gx * (blockIdx.y + gridDim.y * blockIdx.z);
  const int q8 = nwg >> 3, r8 = nwg & 7;
  const int xcd = orig & 7, rank = orig >> 3;
  const int logical = (xcd < r8 ? xcd * (q8 + 1) : r8 * (q8 + 1) + (xcd - r8) * q8) + rank;
  const int wdx_l = logical / gxy;
  const int rem = logical - wdx_l * gxy;
  const int m0 = (rem / gx) * 128, n0 = (rem % gx) * 128;
  const int wdx = wdx_l + wbase;
  const unsigned short* W1w = W1T + (size_t)wdx * CDIM * CDIM;
  unsigned short* Hw = H + (hsel ? (size_t)wdx * MROWS * CDIM : 0);
  const f32x4 z4 = {0.f, 0.f, 0.f, 0.f};
  f32x4 acc[2][4] = {{z4, z4, z4, z4}, {z4, z4, z4, z4}};

  for (int k0 = 0; k0 < CDIM; k0 += 64) {
    __syncthreads();
#pragma unroll
    for (int j = 0; j < 2; j++) {
      int idx = t + j * 512;               // 0..1023
      int row = idx >> 3, col = (idx & 7) * 8;
      gld16(X + (size_t)(m0 + row) * CDIM + k0 + col, As + idx * 8);
      gld16(W1w + (size_t)(n0 + row) * CDIM + k0 + col, Bs + idx * 8);
    }
    __syncthreads();
#pragma unroll
    for (int ks = 0; ks < 2; ks++) {
      bf16x8 a[2], b[4];
#pragma unroll
      for (int mt = 0; mt < 2; mt++)
        a[mt] = *(const bf16x8*)(As + (wm * 32 + mt * 16 + lr) * 64 + ks * 32 + lq * 8);
#pragma unroll
      for (int nt = 0; nt < 4; nt++)
        b[nt] = *(const bf16x8*)(Bs + (wn * 64 + nt * 16 + lr) * 64 + ks * 32 + lq * 8);
#pragma unroll
      for (int mt = 0; mt < 2; mt++)
#pragma unroll
        for (int nt = 0; nt < 4; nt++)
          acc[mt][nt] = __builtin_amdgcn_mfma_f32_16x16x32_bf16(a[mt], b[nt], acc[mt][nt], 0, 0, 0);
    }
  }
#pragma unroll
  for (int mt = 0; mt < 2; mt++)
#pragma unroll
    for (int nt = 0; nt < 4; nt++)
#pragma unroll
      for (int r = 0; r < 4; r++) {
        int m = m0 + wm * 32 + mt * 16 + lq * 4 + r;
        int n = n0 + wn * 64 + nt * 16 + lr;
        Hw[(size_t)m * CDIM + n] = f2bf(fmaxf(acc[mt][nt][r], 0.f));
      }
}

// ---------------------------------------------------------------------------
// gemm2b4: O = H[wdx] @ W2[wdx]. R8 rework of gemm2b3 (the last synchronous-
// staging kernel): BK 64->128 halves barrier-drain count (12->6 K-steps);
// gld16 async staging (unpadded linear layout as gld16 requires -- the
// 16-way read conflicts sit off the critical path in 2-barrier structures,
// same as g1/m97); 512 threads/8 waves (wave tile 16m x 48e, 3 acc frags)
// doubles per-block latency hiding. LDS 16K+24K = 40960 = 4 blocks/CU (max
// waves). vnorm e-split combined via LDS aliased onto As after a barrier.
// ---------------------------------------------------------------------------
__global__ __launch_bounds__(512) void gemm2b4(const unsigned short* __restrict__ H,
                                               const unsigned short* __restrict__ W2T,
                                               unsigned short* __restrict__ QKV,
                                               unsigned short* __restrict__ Kpad,
                                               unsigned short* __restrict__ Vt,
                                               float* __restrict__ vnorm,
                                               int wbase, int hsel) {
  __shared__ __align__(16) unsigned short As[64 * 128];   // 16 KB
  __shared__ __align__(16) unsigned short Bs[96 * 128];   // 24 KB
  const int t = threadIdx.x;
  const int lane = t & 63, w = t >> 6;
  const int lr = lane & 15, lq = lane >> 4;
  const int wm = w & 3, we = w >> 2;      // m quarter (16 rows), e half (48)
  const int m0 = blockIdx.x * 64;
  const int wdx = blockIdx.y + wbase;
  const unsigned short* Hw = H + (hsel ? (size_t)wdx * MROWS * CDIM : 0);
  const unsigned short* W2w = W2T + (size_t)wdx * INNER * CDIM;
  const f32x4 z4 = {0.f, 0.f, 0.f, 0.f};
  f32x4 acc[3] = {z4, z4, z4};

  for (int k0 = 0; k0 < CDIM; k0 += 128) {
    __syncthreads();
    // As: 64x128 = 1024 16B-chunks (2/thread)
#pragma unroll
    for (int j = 0; j < 2; j++) {
      int l = t + j * 512;
      int row = l >> 4, ch = l & 15;
      gld16(Hw + (size_t)(m0 + row) * CDIM + k0 + ch * 8, As + l * 8);
    }
    // Bs: 96x128 = 1536 chunks (3/thread)
#pragma unroll
    for (int j = 0; j < 3; j++) {
      int l = t + j * 512;
      int row = l >> 4, ch = l & 15;
      gld16(W2w + (size_t)row * CDIM + k0 + ch * 8, Bs + l * 8);
    }
    __syncthreads();
#pragma unroll
    for (int kk = 0; kk < 4; kk++) {
      bf16x8 a = *(const bf16x8*)(As + (wm * 16 + lr) * 128 + kk * 32 + lq * 8);
#pragma unroll
      for (int et = 0; et < 3; et++) {
        bf16x8 b = *(const bf16x8*)(Bs + (we * 48 + et * 16 + lr) * 128 + kk * 32 + lq * 8);
        acc[et] = __builtin_amdgcn_mfma_f32_16x16x32_bf16(a, b, acc[et], 0, 0, 0);
      }
    }
  }
  // ---- epilogue: m = m0 + wm*16 + lq*4 + r ; e = we*48 + et*16 + lr
  float nsq[4] = {0.f, 0.f, 0.f, 0.f};
#pragma unroll
  for (int et = 0; et < 3; et++)
#pragma unroll
    for (int r = 0; r < 4; r++) {
      int m = m0 + wm * 16 + lq * 4 + r;
      int e = we * 48 + et * 16 + lr;
      float v = acc[et][r];
      int img = m / 49, s = m - img * 49;
      if (wdx == 0) {
        QKV[(size_t)m * INNER + e] = f2bf(v * SCALE_EXP2);
      } else if (wdx == 1) {
        Kpad[(size_t)(img * 64 + s) * INNER + e] = f2bf(v);
      } else {
        QKV[(size_t)(2 * MROWS + m) * INNER + e] = f2bf(v);
        Vt[(size_t)img * (INNER * 64) + e * 64 + s] = f2bf(v);
        nsq[r] += v * v;
      }
    }
  if (wdx == 2) {                          // wdx uniform per block: barriers safe
    __syncthreads();                       // all waves done reading As
    float (*nsqp)[64] = (float (*)[64])As; // alias As for the e-half combine
#pragma unroll
    for (int r = 0; r < 4; r++) {
      float p = nsq[r];
      p += __shfl_xor(p, 1, 16);
      p += __shfl_xor(p, 2, 16);
      p += __shfl_xor(p, 4, 16);
      p += __shfl_xor(p, 8, 16);
      if (lr == 0) nsqp[we][wm * 16 + lq * 4 + r] = p;
    }
    __syncthreads();
    if (t < 64) vnorm[m0 + t] = sqrtf(nsqp[0][t] + nsqp[1][t]);
  }
}

// ---------------------------------------------------------------------------
// attn11 (verified 90us, R3/R7): K single-buffered, Vt async-staged to LDS,
// 2 barriers/fi, LDS 40960B = 4 blocks/CU, grid 1568, setprio on MFMA.
// ---------------------------------------------------------------------------
__global__ __launch_bounds__(256) void attn11(const unsigned short* __restrict__ Qp,
                                              const unsigned short* __restrict__ Kpad,
                                              const unsigned short* __restrict__ V,
                                              const unsigned short* __restrict__ Vt,
                                              const float* __restrict__ vnorm,
                                              float* __restrict__ cosbuf) {
  __shared__ __align__(16) unsigned short Ks[64 * INNER];      // 12 KB
  __shared__ __align__(16) unsigned short VtS[INNER * 64];     // 12 KB
  __shared__ __align__(16) unsigned short Ps[4][32 * 64];      // 16 KB

  const int t = threadIdx.x;
  const int lane = t & 63, w = t >> 6;
  const int lr = lane & 15, lq = lane >> 4;
  const f32x4 z4 = {0.f, 0.f, 0.f, 0.f};

  int bx = blockIdx.x;
  const int dir = bx / 784; bx -= dir * 784;     // 784 = 49 chunks * 16 fgroups
  const int chunk = bx >> 4, fg = bx & 15;
  const int r0 = chunk * 128;
  const int qbase = dir * NSIDE;

  // ---- staging maps (lds offset is wave-uniform base + lane*16 by constr.)
  int goK[3], goV[3], lo[3];
#pragma unroll
  for (int j = 0; j < 3; j++) {
    int l = (w * 3 + j) * 64 + lane;          // chunk id 0..767
    lo[j] = l * 8;
    int rK = l / 12, scK = l - rK * 12;
    int ccK = scK - ((rK >> 1) & 7); if (ccK < 0) ccK += 12;
    goK[j] = rK * INNER + ccK * 8;
    int rV = l >> 3, scV = l & 7;
    int ccV = (scV - (rV & 7)) & 7;
    goV[j] = rV * 64 + ccV * 8;
  }
  // ---- swizzled read offsets
  int rdK[3], rdV[2];
#pragma unroll
  for (int ks = 0; ks < 3; ks++) {
    int sc = (ks * 4 + lq + ((lr >> 1) & 7)) % 12;
    rdK[ks] = lr * INNER + sc * 8;            // + kt*16*INNER
  }
#pragma unroll
  for (int ks = 0; ks < 2; ks++) {
    int sc = (ks * 4 + lq + (lr & 7)) & 7;
    rdV[ks] = lr * 64 + sc * 8;               // + et*16*64
  }

  // ---- Q fragments into registers (B-operand layout: n=lr, k=ks*32+lq*8)
  bf16x8 qf[2][3];
#pragma unroll
  for (int qt = 0; qt < 2; qt++) {
    const int qrow = qbase + r0 + w * 32 + qt * 16 + lr;
#pragma unroll
    for (int ks = 0; ks < 3; ks++)
      qf[qt][ks] = *(const bf16x8*)(Qp + (size_t)qrow * INNER + ks * 32 + lq * 8);
  }
  // ---- reference V + 1/vnorm into registers (PV D-layout: e=et*16+lq*4+r)
  float rv[2][6][4], invvn[2];
#pragma unroll
  for (int qt = 0; qt < 2; qt++) {
    const int qrow = qbase + r0 + w * 32 + qt * 16 + lr;
    invvn[qt] = 1.f / fmaxf(vnorm[qrow], 1e-8f);
#pragma unroll
    for (int et = 0; et < 6; et++) {
      ushort4 u = *(const ushort4*)(V + (size_t)qrow * INNER + et * 16 + lq * 4);
      rv[qt][et][0] = bf2f(u.x); rv[qt][et][1] = bf2f(u.y);
      rv[qt][et][2] = bf2f(u.z); rv[qt][et][3] = bf2f(u.w);
    }
  }

  unsigned short* Pw = &Ps[w][0];
  const int kimg0 = (dir == 0 ? 128 : 0) + fg * 8;
  // ---- prologue: prefetch K[0]
  {
    const unsigned short* kg = Kpad + (size_t)kimg0 * (64 * INNER);
#pragma unroll
    for (int j = 0; j < 3; j++) gld16(kg + goK[j], Ks + lo[j]);
  }
  for (int fi = 0; fi < 8; fi++) {
    const int f = fg * 8 + fi;
    __syncthreads();   // (1) drains K[fi]; prev PV done by all waves
    // ---- issue Vt[fi] into single buffer (async; drained at barrier 2)
    {
      const unsigned short* vg = Vt + (size_t)(kimg0 + fi) * (INNER * 64);
#pragma unroll
      for (int j = 0; j < 3; j++) gld16(vg + goV[j], VtS + lo[j]);
    }
    // ---- S^T = K @ Q^T : each a-fragment feeds BOTH q-tiles
    f32x4 s4[2][4] = {{z4, z4, z4, z4}, {z4, z4, z4, z4}};
    __builtin_amdgcn_s_setprio(1);
#pragma unroll
    for (int ks = 0; ks < 3; ks++) {
#pragma unroll
      for (int kt = 0; kt < 4; kt++) {
        bf16x8 a = *(const bf16x8*)(Ks + kt * (16 * INNER) + rdK[ks]);
        s4[0][kt] = __builtin_amdgcn_mfma_f32_16x16x32_bf16(a, qf[0][ks], s4[0][kt], 0, 0, 0);
        s4[1][kt] = __builtin_amdgcn_mfma_f32_16x16x32_bf16(a, qf[1][ks], s4[1][kt], 0, 0, 0);
      }
    }
    __builtin_amdgcn_s_setprio(0);
    // ---- P[q][k] = exp2(S^T) -> Ps (XOR-chunk swizzled, wave-private)
#pragma unroll
    for (int qt = 0; qt < 2; qt++)
#pragma unroll
      for (int kt = 0; kt < 4; kt++) {
        float e0 = __builtin_exp2f(s4[qt][kt][0]);
        float e1 = __builtin_exp2f(s4[qt][kt][1]);
        float e2 = __builtin_exp2f(s4[qt][kt][2]);
        float e3 = __builtin_exp2f(s4[qt][kt][3]);
        uint2 pk = make_uint2(pack_bf16_rn(e0, e1), pack_bf16_rn(e2, e3));
        int row = qt * 16 + lr;
        int ch = (2 * kt + (lq >> 1)) ^ (row & 7);
        *(uint2*)(Pw + row * 64 + ch * 8 + (lq & 1) * 4) = pk;
      }
    __syncthreads();   // (2) drains Vt[fi]; all waves' K reads done
    // ---- issue K prefetch for f+1 AFTER barrier 2 (same buffer is safe:
    //      every wave's QK^T reads completed before barrier 2)
    if (fi < 7) {
      const unsigned short* kg = Kpad + (size_t)(kimg0 + fi + 1) * (64 * INNER);
#pragma unroll
      for (int j = 0; j < 3; j++) gld16(kg + goK[j], Ks + lo[j]);
    }
    // ---- aligned^T[e][q] = Vt @ P^T (a-fragment reused 2x)
    f32x4 pv[2][6] = {{z4, z4, z4, z4, z4, z4}, {z4, z4, z4, z4, z4, z4}};
    __builtin_amdgcn_s_setprio(1);
#pragma unroll
    for (int ks = 0; ks < 2; ks++) {
      int row0 = 0 * 16 + lr, row1 = 1 * 16 + lr;
      int ch0 = ((ks * 4 + lq) ^ (row0 & 7));
      int ch1 = ((ks * 4 + lq) ^ (row1 & 7));
      bf16x8 b0 = *(const bf16x8*)(Pw + row0 * 64 + ch0 * 8);
      bf16x8 b1 = *(const bf16x8*)(Pw + row1 * 64 + ch1 * 8);
#pragma unroll
      for (int et = 0; et < 6; et++) {
        bf16x8 a = *(const bf16x8*)(VtS + et * (16 * 64) + rdV[ks]);
        pv[0][et] = __builtin_amdgcn_mfma_f32_16x16x32_bf16(a, b0, pv[0][et], 0, 0, 0);
        pv[1][et] = __builtin_amdgcn_mfma_f32_16x16x32_bf16(a, b1, pv[1][et], 0, 0, 0);
      }
    }
    __builtin_amdgcn_s_setprio(0);
    // ---- cosine epilogue per q-tile: lane owns query q=lr
#pragma unroll
    for (int qt = 0; qt < 2; qt++) {
      float d = 0.f, nn = 0.f;
#pragma unroll
      for (int et = 0; et < 6; et++)
#pragma unroll
        for (int r = 0; r < 4; r++) {
          float al = pv[qt][et][r];
          d += al * rv[qt][et][r];
          nn += al * al;
        }
      d += __shfl_xor(d, 16, 64);  d += __shfl_xor(d, 32, 64);
      nn += __shfl_xor(nn, 16, 64); nn += __shfl_xor(nn, 32, 64);
      if (lane < 16) {
        float cv = d * __frsqrt_rn(fmaxf(nn, 1e-40f)) * invvn[qt];
        cosbuf[(size_t)(dir * 128 + f) * NSIDE + r0 + w * 32 + qt * 16 + lr] = cv;
      }
    }
  }
}

// ---------------------------------------------------------------------------
// reduce_out: out[bb*128+aa] = (sum_q cos0[bb][aa*49+q] + cos1[aa][bb*49+q])/49
// ---------------------------------------------------------------------------
__global__ __launch_bounds__(256) void reduce_out(const float* __restrict__ cosbuf,
                                                  float* __restrict__ out) {
  const int t = threadIdx.x, lane = t & 63, wv = t >> 6;
  const int pair = blockIdx.x * 4 + wv;
  const int bb = pair >> 7, aa = pair & 127;
  float v = 0.f;
  if (lane < S49) {
    v  = cosbuf[(size_t)bb * NSIDE + aa * S49 + lane];
    v += cosbuf[(size_t)(128 + aa) * NSIDE + bb * S49 + lane];
  }
  for (int m = 1; m < 64; m <<= 1) v += __shfl_xor(v, m, 64);
  if (lane == 0) out[pair] = v * (1.f / 49.f);
}

// ---------------------------------------------------------------------------
extern "C" void kernel_launch(void* const* d_in, const int* in_sizes, int n_in,
                              void* d_out, int out_size, void* d_ws, size_t ws_size,
                              hipStream_t stream) {
  const float* fa  = (const float*)d_in[0];
  const float* fb  = (const float*)d_in[1];
  const float* W1[3] = {(const float*)d_in[2], (const float*)d_in[4], (const float*)d_in[6]};
  const float* W2[3] = {(const float*)d_in[3], (const float*)d_in[5], (const float*)d_in[7]};
  float* out = (float*)d_out;

  unsigned short* p = (unsigned short*)d_ws;
  unsigned short* Xbf = p;                 p += (size_t)MROWS * CDIM;      // 19.3 MB
  unsigned short* W1T = p;                 p += (size_t)3 * CDIM * CDIM;   // 3.5 MB
  unsigned short* W2T = p;                 p += (size_t)3 * INNER * CDIM;  // 0.44 MB
  unsigned short* QKV = p;                 p += (size_t)3 * MROWS * INNER; // 7.2 MB
  unsigned short* Vt  = p;                 p += (size_t)256 * INNER * 64;  // 3.1 MB
  unsigned short* Kpad = p;                p += (size_t)256 * 64 * INNER;  // 3.1 MB (adjacent to Vt!)
  float* vnorm = (float*)p;                p += (size_t)MROWS * 2;         // 50 KB
  float* cosbuf = (float*)p;               p += (size_t)256 * NSIDE * 2;   // 6.4 MB
  unsigned short* H = p;                   p += (size_t)3 * MROWS * CDIM;  // 57.8 MB (batched)
  const size_t need_batched = (size_t)(p - (unsigned short*)d_ws) * 2;
  const int batched = ws_size >= need_batched;

  prep_all<<<dim3(5112), 256, 0, stream>>>(fa, fb, W1[0], W1[1], W1[2],
                                           W2[0], W2[1], W2[2],
                                           Xbf, W1T, W2T, Vt /* VtKpad span */);
  if (batched) {
    gemm1b4<<<dim3(CDIM / 128, MROWS / 128, 3), 512, 0, stream>>>(Xbf, W1T, H, 0, 1);
    gemm2b4<<<dim3(MROWS / 64, 3), 512, 0, stream>>>(H, W2T, QKV, Kpad, Vt, vnorm, 0, 1);
  } else {
    for (int wdx = 0; wdx < 3; wdx++) {
      gemm1b4<<<dim3(CDIM / 128, MROWS / 128, 1), 512, 0, stream>>>(Xbf, W1T, H, wdx, 0);
      gemm2b4<<<dim3(MROWS / 64, 1), 512, 0, stream>>>(H, W2T, QKV, Kpad, Vt, vnorm, wdx, 0);
    }
  }
  attn11<<<dim3(2 * 784), 256, 0, stream>>>(
      QKV, Kpad, QKV + (size_t)2 * MROWS * INNER, Vt, vnorm, cosbuf);
  reduce_out<<<dim3(4096), 256, 0, stream>>>(cosbuf, out);
}

// Round 9
// 278.242 us; speedup vs baseline: 1.0851x; 1.0851x over previous
//
#include <hip/hip_runtime.h>
#include <hip/hip_bf16.h>
#include <math.h>

typedef __attribute__((ext_vector_type(8))) short bf16x8;
typedef __attribute__((ext_vector_type(4))) float f32x4;

#define MROWS 12544      // (128+128)*49
#define CDIM 768
#define INNER 96
#define S49 49
#define NSIDE 6272       // 128*49 rows per side
#define SCALE 0.10206207261596577f
// SCALE * log2(e): Q prescale so attn can use exp2 directly
#define SCALE_EXP2 ((float)(0.10206207261596577 * 1.4426950408889634))

__device__ __forceinline__ unsigned short f2bf(float f) {
  union { float f; unsigned u; } v; v.f = f;
  unsigned u = v.u;
  return (unsigned short)((u + 0x7fffu + ((u >> 16) & 1u)) >> 16);
}
__device__ __forceinline__ float bf2f(unsigned short h) {
  union { unsigned u; float f; } v; v.u = ((unsigned)h) << 16;
  return v.f;
}
// pack two floats to bf16x2 (round-to-nearest-ish): low=a, high=b
__device__ __forceinline__ unsigned pack_bf16_rn(float a, float b) {
  union { float f; unsigned u; } ua, ub; ua.f = a; ub.f = b;
  return __builtin_amdgcn_perm(ub.u + 0x8000u, ua.u + 0x8000u, 0x07060302u);
}

// async global->LDS, 16B per lane. Dest must be wave-uniform base + lane*16.
__device__ __forceinline__ void gld16(const unsigned short* g, unsigned short* l) {
  __builtin_amdgcn_global_load_lds(
      (const __attribute__((address_space(1))) unsigned int*)(g),
      (__attribute__((address_space(3))) unsigned int*)(l), 16, 0, 0);
}

// ---------------------------------------------------------------------------
// prep_all: one kernel, three phases by block range.
// ---------------------------------------------------------------------------
__global__ __launch_bounds__(256) void prep_all(
    const float* __restrict__ fa, const float* __restrict__ fb,
    const float* __restrict__ w10, const float* __restrict__ w11,
    const float* __restrict__ w12, const float* __restrict__ w20,
    const float* __restrict__ w21, const float* __restrict__ w22,
    unsigned short* __restrict__ X,
    unsigned short* __restrict__ W1T, unsigned short* __restrict__ W2T,
    unsigned short* __restrict__ VtKpad) {
  const int t = threadIdx.x;
  int id = blockIdx.x;
  if (id < 3072) {
    __shared__ float T[64][50];
    const int z = id / 1536; id -= z * 1536;
    const int ct = id % 12, img = id / 12;
    const float* feat = z ? fb : fa;
    const float* src = feat + (size_t)img * (CDIM * S49) + (size_t)ct * 64 * S49;
    for (int idx = t; idx < 64 * S49; idx += 256) {
      int cc = idx / S49, s = idx - cc * S49;
      T[cc][s] = src[cc * S49 + s];
    }
    __syncthreads();
    unsigned short* dst = X + (size_t)(z * 128 + img) * S49 * CDIM + ct * 64;
    for (int idx = t; idx < S49 * 64; idx += 256) {
      int s = idx >> 6, cc = idx & 63;
      dst[(size_t)s * CDIM + cc] = f2bf(T[cc][s]);
    }
  } else if (id < 5016) {
    __shared__ float T[32][33];
    id -= 3072;
    const float* src;
    unsigned short* dst;
    int C, ctile, rtile;
    if (id < 1728) {
      int wdx = id / 576, tid = id - wdx * 576;
      ctile = tid % 24; rtile = tid / 24;
      src = wdx == 0 ? w10 : (wdx == 1 ? w11 : w12);
      dst = W1T + (size_t)wdx * CDIM * CDIM;
      C = CDIM;
    } else {
      id -= 1728;
      int wdx = id / 72, tid = id - wdx * 72;
      ctile = tid % 3; rtile = tid / 3;
      src = wdx == 0 ? w20 : (wdx == 1 ? w21 : w22);
      dst = W2T + (size_t)wdx * INNER * CDIM;
      C = INNER;
    }
    const int c0 = ctile * 32, r0 = rtile * 32;
    for (int idx = t; idx < 1024; idx += 256) {
      int rr = idx >> 5, cc = idx & 31;
      T[rr][cc] = src[(size_t)(r0 + rr) * C + c0 + cc];
    }
    __syncthreads();
    for (int idx = t; idx < 1024; idx += 256) {
      int rr = idx >> 5, cc = idx & 31;
      dst[(size_t)(c0 + rr) * CDIM + r0 + cc] = f2bf(T[cc][rr]);
    }
  } else {
    id -= 5016;
    ushort4* p4 = (ushort4*)VtKpad;
    const ushort4 z = make_ushort4(0, 0, 0, 0);
#pragma unroll
    for (int i = 0; i < 32; i++)
      p4[(size_t)id * 8192 + i * 256 + t] = z;
  }
}

// ---------------------------------------------------------------------------
// gemm1b4: H[wdx] = relu(X @ W1[wdx]). 128x128 tile, BK=64, gld16 staging.
// Bijective XCD-chunked swizzle (T1/m204): verified WIN in R7 (+10us).
// ---------------------------------------------------------------------------
__global__ __launch_bounds__(512) void gemm1b4(const unsigned short* __restrict__ X,
                                               const unsigned short* __restrict__ W1T,
                                               unsigned short* __restrict__ H,
                                               int wbase, int hsel) {
  __shared__ __align__(16) unsigned short As[128 * 64];
  __shared__ __align__(16) unsigned short Bs[128 * 64];
  const int t = threadIdx.x;
  const int lane = t & 63, w = t >> 6;
  const int lr = lane & 15, lq = lane >> 4;
  const int wm = w & 3;          // m quarter (32 rows)
  const int wn = w >> 2;         // n half (64 cols)
  // ---- bijective XCD swizzle over the full grid (m204 formula)
  const int gx = gridDim.x, gxy = gx * gridDim.y;
  const int nwg = gxy * gridDim.z;
  const int orig = blockIdx.x + gx * (blockIdx.y + gridDim.y * blockIdx.z);
  const int q8 = nwg >> 3, r8 = nwg & 7;
  const int xcd = orig & 7, rank = orig >> 3;
  const int logical = (xcd < r8 ? xcd * (q8 + 1) : r8 * (q8 + 1) + (xcd - r8) * q8) + rank;
  const int wdx_l = logical / gxy;
  const int rem = logical - wdx_l * gxy;
  const int m0 = (rem / gx) * 128, n0 = (rem % gx) * 128;
  const int wdx = wdx_l + wbase;
  const unsigned short* W1w = W1T + (size_t)wdx * CDIM * CDIM;
  unsigned short* Hw = H + (hsel ? (size_t)wdx * MROWS * CDIM : 0);
  const f32x4 z4 = {0.f, 0.f, 0.f, 0.f};
  f32x4 acc[2][4] = {{z4, z4, z4, z4}, {z4, z4, z4, z4}};

  for (int k0 = 0; k0 < CDIM; k0 += 64) {
    __syncthreads();
#pragma unroll
    for (int j = 0; j < 2; j++) {
      int idx = t + j * 512;               // 0..1023
      int row = idx >> 3, col = (idx & 7) * 8;
      gld16(X + (size_t)(m0 + row) * CDIM + k0 + col, As + idx * 8);
      gld16(W1w + (size_t)(n0 + row) * CDIM + k0 + col, Bs + idx * 8);
    }
    __syncthreads();
#pragma unroll
    for (int ks = 0; ks < 2; ks++) {
      bf16x8 a[2], b[4];
#pragma unroll
      for (int mt = 0; mt < 2; mt++)
        a[mt] = *(const bf16x8*)(As + (wm * 32 + mt * 16 + lr) * 64 + ks * 32 + lq * 8);
#pragma unroll
      for (int nt = 0; nt < 4; nt++)
        b[nt] = *(const bf16x8*)(Bs + (wn * 64 + nt * 16 + lr) * 64 + ks * 32 + lq * 8);
#pragma unroll
      for (int mt = 0; mt < 2; mt++)
#pragma unroll
        for (int nt = 0; nt < 4; nt++)
          acc[mt][nt] = __builtin_amdgcn_mfma_f32_16x16x32_bf16(a[mt], b[nt], acc[mt][nt], 0, 0, 0);
    }
  }
#pragma unroll
  for (int mt = 0; mt < 2; mt++)
#pragma unroll
    for (int nt = 0; nt < 4; nt++)
#pragma unroll
      for (int r = 0; r < 4; r++) {
        int m = m0 + wm * 32 + mt * 16 + lq * 4 + r;
        int n = n0 + wn * 64 + nt * 16 + lr;
        Hw[(size_t)m * CDIM + n] = f2bf(fmaxf(acc[mt][nt][r], 0.f));
      }
}

// ---------------------------------------------------------------------------
// gemm2b5: O = H[wdx] @ W2[wdx]. R9 = R8's gemm2b4 + rule-#21 swizzle fix.
// R8 post-mortem: unpadded linear reads at stride 256B were a 16-way bank
// conflict; at 32 waves/CU the LDS pipe saturated (-10us vs padded b3).
// Fix: gld16 keeps LINEAR LDS dest; per-lane GLOBAL source XORs the 16B
// chunk with (row&7); reads apply the same XOR -> 2-way (free). Same
// pattern as attn11's K staging (verified). BK=128 (6 K-steps), 512 thr /
// 8 waves, LDS 40960 = 4 blocks/CU.
// ---------------------------------------------------------------------------
__global__ __launch_bounds__(512) void gemm2b5(const unsigned short* __restrict__ H,
                                               const unsigned short* __restrict__ W2T,
                                               unsigned short* __restrict__ QKV,
                                               unsigned short* __restrict__ Kpad,
                                               unsigned short* __restrict__ Vt,
                                               float* __restrict__ vnorm,
                                               int wbase, int hsel) {
  __shared__ __align__(16) unsigned short As[64 * 128];   // 16 KB
  __shared__ __align__(16) unsigned short Bs[96 * 128];   // 24 KB
  const int t = threadIdx.x;
  const int lane = t & 63, w = t >> 6;
  const int lr = lane & 15, lq = lane >> 4;
  const int wm = w & 3, we = w >> 2;      // m quarter (16 rows), e half (48)
  const int m0 = blockIdx.x * 64;
  const int wdx = blockIdx.y + wbase;
  const unsigned short* Hw = H + (hsel ? (size_t)wdx * MROWS * CDIM : 0);
  const unsigned short* W2w = W2T + (size_t)wdx * INNER * CDIM;
  const f32x4 z4 = {0.f, 0.f, 0.f, 0.f};
  f32x4 acc[3] = {z4, z4, z4};

  for (int k0 = 0; k0 < CDIM; k0 += 128) {
    __syncthreads();
    // As: 64x128 = 1024 16B-chunks (2/thread); source-preswizzled ch^(row&7)
#pragma unroll
    for (int j = 0; j < 2; j++) {
      int l = t + j * 512;
      int row = l >> 4, ch = l & 15;
      gld16(Hw + (size_t)(m0 + row) * CDIM + k0 + (ch ^ (row & 7)) * 8, As + l * 8);
    }
    // Bs: 96x128 = 1536 chunks (3/thread); same preswizzle on e-row
#pragma unroll
    for (int j = 0; j < 3; j++) {
      int l = t + j * 512;
      int row = l >> 4, ch = l & 15;
      gld16(W2w + (size_t)row * CDIM + k0 + (ch ^ (row & 7)) * 8, Bs + l * 8);
    }
    __syncthreads();
#pragma unroll
    for (int kk = 0; kk < 4; kk++) {
      // row bases (wm*16, we*48, et*16) are all 0 mod 8 -> row&7 == lr&7
      int ca = (kk * 4 + lq) ^ (lr & 7);
      bf16x8 a = *(const bf16x8*)(As + (wm * 16 + lr) * 128 + ca * 8);
#pragma unroll
      for (int et = 0; et < 3; et++) {
        bf16x8 b = *(const bf16x8*)(Bs + (we * 48 + et * 16 + lr) * 128 + ca * 8);
        acc[et] = __builtin_amdgcn_mfma_f32_16x16x32_bf16(a, b, acc[et], 0, 0, 0);
      }
    }
  }
  // ---- epilogue: m = m0 + wm*16 + lq*4 + r ; e = we*48 + et*16 + lr
  float nsq[4] = {0.f, 0.f, 0.f, 0.f};
#pragma unroll
  for (int et = 0; et < 3; et++)
#pragma unroll
    for (int r = 0; r < 4; r++) {
      int m = m0 + wm * 16 + lq * 4 + r;
      int e = we * 48 + et * 16 + lr;
      float v = acc[et][r];
      int img = m / 49, s = m - img * 49;
      if (wdx == 0) {
        QKV[(size_t)m * INNER + e] = f2bf(v * SCALE_EXP2);
      } else if (wdx == 1) {
        Kpad[(size_t)(img * 64 + s) * INNER + e] = f2bf(v);
      } else {
        QKV[(size_t)(2 * MROWS + m) * INNER + e] = f2bf(v);
        Vt[(size_t)img * (INNER * 64) + e * 64 + s] = f2bf(v);
        nsq[r] += v * v;
      }
    }
  if (wdx == 2) {                          // wdx uniform per block: barriers safe
    __syncthreads();                       // all waves done reading As
    float (*nsqp)[64] = (float (*)[64])As; // alias As for the e-half combine
#pragma unroll
    for (int r = 0; r < 4; r++) {
      float p = nsq[r];
      p += __shfl_xor(p, 1, 16);
      p += __shfl_xor(p, 2, 16);
      p += __shfl_xor(p, 4, 16);
      p += __shfl_xor(p, 8, 16);
      if (lr == 0) nsqp[we][wm * 16 + lq * 4 + r] = p;
    }
    __syncthreads();
    if (t < 64) vnorm[m0 + t] = sqrtf(nsqp[0][t] + nsqp[1][t]);
  }
}

// ---------------------------------------------------------------------------
// attn11 (verified ~90us, R3/R7/R8): K single-buffered, Vt async-staged to
// LDS, 2 barriers/fi, LDS 40960B = 4 blocks/CU, grid 1568, setprio on MFMA.
// ---------------------------------------------------------------------------
__global__ __launch_bounds__(256) void attn11(const unsigned short* __restrict__ Qp,
                                              const unsigned short* __restrict__ Kpad,
                                              const unsigned short* __restrict__ V,
                                              const unsigned short* __restrict__ Vt,
                                              const float* __restrict__ vnorm,
                                              float* __restrict__ cosbuf) {
  __shared__ __align__(16) unsigned short Ks[64 * INNER];      // 12 KB
  __shared__ __align__(16) unsigned short VtS[INNER * 64];     // 12 KB
  __shared__ __align__(16) unsigned short Ps[4][32 * 64];      // 16 KB

  const int t = threadIdx.x;
  const int lane = t & 63, w = t >> 6;
  const int lr = lane & 15, lq = lane >> 4;
  const f32x4 z4 = {0.f, 0.f, 0.f, 0.f};

  int bx = blockIdx.x;
  const int dir = bx / 784; bx -= dir * 784;     // 784 = 49 chunks * 16 fgroups
  const int chunk = bx >> 4, fg = bx & 15;
  const int r0 = chunk * 128;
  const int qbase = dir * NSIDE;

  // ---- staging maps (lds offset is wave-uniform base + lane*16 by constr.)
  int goK[3], goV[3], lo[3];
#pragma unroll
  for (int j = 0; j < 3; j++) {
    int l = (w * 3 + j) * 64 + lane;          // chunk id 0..767
    lo[j] = l * 8;
    int rK = l / 12, scK = l - rK * 12;
    int ccK = scK - ((rK >> 1) & 7); if (ccK < 0) ccK += 12;
    goK[j] = rK * INNER + ccK * 8;
    int rV = l >> 3, scV = l & 7;
    int ccV = (scV - (rV & 7)) & 7;
    goV[j] = rV * 64 + ccV * 8;
  }
  // ---- swizzled read offsets
  int rdK[3], rdV[2];
#pragma unroll
  for (int ks = 0; ks < 3; ks++) {
    int sc = (ks * 4 + lq + ((lr >> 1) & 7)) % 12;
    rdK[ks] = lr * INNER + sc * 8;            // + kt*16*INNER
  }
#pragma unroll
  for (int ks = 0; ks < 2; ks++) {
    int sc = (ks * 4 + lq + (lr & 7)) & 7;
    rdV[ks] = lr * 64 + sc * 8;               // + et*16*64
  }

  // ---- Q fragments into registers (B-operand layout: n=lr, k=ks*32+lq*8)
  bf16x8 qf[2][3];
#pragma unroll
  for (int qt = 0; qt < 2; qt++) {
    const int qrow = qbase + r0 + w * 32 + qt * 16 + lr;
#pragma unroll
    for (int ks = 0; ks < 3; ks++)
      qf[qt][ks] = *(const bf16x8*)(Qp + (size_t)qrow * INNER + ks * 32 + lq * 8);
  }
  // ---- reference V + 1/vnorm into registers (PV D-layout: e=et*16+lq*4+r)
  float rv[2][6][4], invvn[2];
#pragma unroll
  for (int qt = 0; qt < 2; qt++) {
    const int qrow = qbase + r0 + w * 32 + qt * 16 + lr;
    invvn[qt] = 1.f / fmaxf(vnorm[qrow], 1e-8f);
#pragma unroll
    for (int et = 0; et < 6; et++) {
      ushort4 u = *(const ushort4*)(V + (size_t)qrow * INNER + et * 16 + lq * 4);
      rv[qt][et][0] = bf2f(u.x); rv[qt][et][1] = bf2f(u.y);
      rv[qt][et][2] = bf2f(u.z); rv[qt][et][3] = bf2f(u.w);
    }
  }

  unsigned short* Pw = &Ps[w][0];
  const int kimg0 = (dir == 0 ? 128 : 0) + fg * 8;
  // ---- prologue: prefetch K[0]
  {
    const unsigned short* kg = Kpad + (size_t)kimg0 * (64 * INNER);
#pragma unroll
    for (int j = 0; j < 3; j++) gld16(kg + goK[j], Ks + lo[j]);
  }
  for (int fi = 0; fi < 8; fi++) {
    const int f = fg * 8 + fi;
    __syncthreads();   // (1) drains K[fi]; prev PV done by all waves
    // ---- issue Vt[fi] into single buffer (async; drained at barrier 2)
    {
      const unsigned short* vg = Vt + (size_t)(kimg0 + fi) * (INNER * 64);
#pragma unroll
      for (int j = 0; j < 3; j++) gld16(vg + goV[j], VtS + lo[j]);
    }
    // ---- S^T = K @ Q^T : each a-fragment feeds BOTH q-tiles
    f32x4 s4[2][4] = {{z4, z4, z4, z4}, {z4, z4, z4, z4}};
    __builtin_amdgcn_s_setprio(1);
#pragma unroll
    for (int ks = 0; ks < 3; ks++) {
#pragma unroll
      for (int kt = 0; kt < 4; kt++) {
        bf16x8 a = *(const bf16x8*)(Ks + kt * (16 * INNER) + rdK[ks]);
        s4[0][kt] = __builtin_amdgcn_mfma_f32_16x16x32_bf16(a, qf[0][ks], s4[0][kt], 0, 0, 0);
        s4[1][kt] = __builtin_amdgcn_mfma_f32_16x16x32_bf16(a, qf[1][ks], s4[1][kt], 0, 0, 0);
      }
    }
    __builtin_amdgcn_s_setprio(0);
    // ---- P[q][k] = exp2(S^T) -> Ps (XOR-chunk swizzled, wave-private)
#pragma unroll
    for (int qt = 0; qt < 2; qt++)
#pragma unroll
      for (int kt = 0; kt < 4; kt++) {
        float e0 = __builtin_exp2f(s4[qt][kt][0]);
        float e1 = __builtin_exp2f(s4[qt][kt][1]);
        float e2 = __builtin_exp2f(s4[qt][kt][2]);
        float e3 = __builtin_exp2f(s4[qt][kt][3]);
        uint2 pk = make_uint2(pack_bf16_rn(e0, e1), pack_bf16_rn(e2, e3));
        int row = qt * 16 + lr;
        int ch = (2 * kt + (lq >> 1)) ^ (row & 7);
        *(uint2*)(Pw + row * 64 + ch * 8 + (lq & 1) * 4) = pk;
      }
    __syncthreads();   // (2) drains Vt[fi]; all waves' K reads done
    // ---- issue K prefetch for f+1 AFTER barrier 2 (same buffer is safe:
    //      every wave's QK^T reads completed before barrier 2)
    if (fi < 7) {
      const unsigned short* kg = Kpad + (size_t)(kimg0 + fi + 1) * (64 * INNER);
#pragma unroll
      for (int j = 0; j < 3; j++) gld16(kg + goK[j], Ks + lo[j]);
    }
    // ---- aligned^T[e][q] = Vt @ P^T (a-fragment reused 2x)
    f32x4 pv[2][6] = {{z4, z4, z4, z4, z4, z4}, {z4, z4, z4, z4, z4, z4}};
    __builtin_amdgcn_s_setprio(1);
#pragma unroll
    for (int ks = 0; ks < 2; ks++) {
      int row0 = 0 * 16 + lr, row1 = 1 * 16 + lr;
      int ch0 = ((ks * 4 + lq) ^ (row0 & 7));
      int ch1 = ((ks * 4 + lq) ^ (row1 & 7));
      bf16x8 b0 = *(const bf16x8*)(Pw + row0 * 64 + ch0 * 8);
      bf16x8 b1 = *(const bf16x8*)(Pw + row1 * 64 + ch1 * 8);
#pragma unroll
      for (int et = 0; et < 6; et++) {
        bf16x8 a = *(const bf16x8*)(VtS + et * (16 * 64) + rdV[ks]);
        pv[0][et] = __builtin_amdgcn_mfma_f32_16x16x32_bf16(a, b0, pv[0][et], 0, 0, 0);
        pv[1][et] = __builtin_amdgcn_mfma_f32_16x16x32_bf16(a, b1, pv[1][et], 0, 0, 0);
      }
    }
    __builtin_amdgcn_s_setprio(0);
    // ---- cosine epilogue per q-tile: lane owns query q=lr
#pragma unroll
    for (int qt = 0; qt < 2; qt++) {
      float d = 0.f, nn = 0.f;
#pragma unroll
      for (int et = 0; et < 6; et++)
#pragma unroll
        for (int r = 0; r < 4; r++) {
          float al = pv[qt][et][r];
          d += al * rv[qt][et][r];
          nn += al * al;
        }
      d += __shfl_xor(d, 16, 64);  d += __shfl_xor(d, 32, 64);
      nn += __shfl_xor(nn, 16, 64); nn += __shfl_xor(nn, 32, 64);
      if (lane < 16) {
        float cv = d * __frsqrt_rn(fmaxf(nn, 1e-40f)) * invvn[qt];
        cosbuf[(size_t)(dir * 128 + f) * NSIDE + r0 + w * 32 + qt * 16 + lr] = cv;
      }
    }
  }
}

// ---------------------------------------------------------------------------
// reduce_out: out[bb*128+aa] = (sum_q cos0[bb][aa*49+q] + cos1[aa][bb*49+q])/49
// ---------------------------------------------------------------------------
__global__ __launch_bounds__(256) void reduce_out(const float* __restrict__ cosbuf,
                                                  float* __restrict__ out) {
  const int t = threadIdx.x, lane = t & 63, wv = t >> 6;
  const int pair = blockIdx.x * 4 + wv;
  const int bb = pair >> 7, aa = pair & 127;
  float v = 0.f;
  if (lane < S49) {
    v  = cosbuf[(size_t)bb * NSIDE + aa * S49 + lane];
    v += cosbuf[(size_t)(128 + aa) * NSIDE + bb * S49 + lane];
  }
  for (int m = 1; m < 64; m <<= 1) v += __shfl_xor(v, m, 64);
  if (lane == 0) out[pair] = v * (1.f / 49.f);
}

// ---------------------------------------------------------------------------
extern "C" void kernel_launch(void* const* d_in, const int* in_sizes, int n_in,
                              void* d_out, int out_size, void* d_ws, size_t ws_size,
                              hipStream_t stream) {
  const float* fa  = (const float*)d_in[0];
  const float* fb  = (const float*)d_in[1];
  const float* W1[3] = {(const float*)d_in[2], (const float*)d_in[4], (const float*)d_in[6]};
  const float* W2[3] = {(const float*)d_in[3], (const float*)d_in[5], (const float*)d_in[7]};
  float* out = (float*)d_out;

  unsigned short* p = (unsigned short*)d_ws;
  unsigned short* Xbf = p;                 p += (size_t)MROWS * CDIM;      // 19.3 MB
  unsigned short* W1T = p;                 p += (size_t)3 * CDIM * CDIM;   // 3.5 MB
  unsigned short* W2T = p;                 p += (size_t)3 * INNER * CDIM;  // 0.44 MB
  unsigned short* QKV = p;                 p += (size_t)3 * MROWS * INNER; // 7.2 MB
  unsigned short* Vt  = p;                 p += (size_t)256 * INNER * 64;  // 3.1 MB
  unsigned short* Kpad = p;                p += (size_t)256 * 64 * INNER;  // 3.1 MB (adjacent to Vt!)
  float* vnorm = (float*)p;                p += (size_t)MROWS * 2;         // 50 KB
  float* cosbuf = (float*)p;               p += (size_t)256 * NSIDE * 2;   // 6.4 MB
  unsigned short* H = p;                   p += (size_t)3 * MROWS * CDIM;  // 57.8 MB (batched)
  const size_t need_batched = (size_t)(p - (unsigned short*)d_ws) * 2;
  const int batched = ws_size >= need_batched;

  prep_all<<<dim3(5112), 256, 0, stream>>>(fa, fb, W1[0], W1[1], W1[2],
                                           W2[0], W2[1], W2[2],
                                           Xbf, W1T, W2T, Vt /* VtKpad span */);
  if (batched) {
    gemm1b4<<<dim3(CDIM / 128, MROWS / 128, 3), 512, 0, stream>>>(Xbf, W1T, H, 0, 1);
    gemm2b5<<<dim3(MROWS / 64, 3), 512, 0, stream>>>(H, W2T, QKV, Kpad, Vt, vnorm, 0, 1);
  } else {
    for (int wdx = 0; wdx < 3; wdx++) {
      gemm1b4<<<dim3(CDIM / 128, MROWS / 128, 1), 512, 0, stream>>>(Xbf, W1T, H, wdx, 0);
      gemm2b5<<<dim3(MROWS / 64, 1), 512, 0, stream>>>(H, W2T, QKV, Kpad, Vt, vnorm, wdx, 0);
    }
  }
  attn11<<<dim3(2 * 784), 256, 0, stream>>>(
      QKV, Kpad, QKV + (size_t)2 * MROWS * INNER, Vt, vnorm, cosbuf);
  reduce_out<<<dim3(4096), 256, 0, stream>>>(cosbuf, out);
}

// Round 10
// 259.076 us; speedup vs baseline: 1.1653x; 1.0740x over previous
//
#include <hip/hip_runtime.h>
#include <hip/hip_bf16.h>
#include <math.h>

typedef __attribute__((ext_vector_type(8))) short bf16x8;
typedef __attribute__((ext_vector_type(4))) float f32x4;

#define MROWS 12544      // (128+128)*49
#define CDIM 768
#define INNER 96
#define S49 49
#define NSIDE 6272       // 128*49 rows per side
#define SCALE 0.10206207261596577f
// SCALE * log2(e): Q prescale so attn can use exp2 directly
#define SCALE_EXP2 ((float)(0.10206207261596577 * 1.4426950408889634))

__device__ __forceinline__ unsigned short f2bf(float f) {
  union { float f; unsigned u; } v; v.f = f;
  unsigned u = v.u;
  return (unsigned short)((u + 0x7fffu + ((u >> 16) & 1u)) >> 16);
}
__device__ __forceinline__ float bf2f(unsigned short h) {
  union { unsigned u; float f; } v; v.u = ((unsigned)h) << 16;
  return v.f;
}
// pack two floats to bf16x2 (round-to-nearest-ish): low=a, high=b
__device__ __forceinline__ unsigned pack_bf16_rn(float a, float b) {
  union { float f; unsigned u; } ua, ub; ua.f = a; ub.f = b;
  return __builtin_amdgcn_perm(ub.u + 0x8000u, ua.u + 0x8000u, 0x07060302u);
}

// async global->LDS, 16B per lane. Dest must be wave-uniform base + lane*16.
__device__ __forceinline__ void gld16(const unsigned short* g, unsigned short* l) {
  __builtin_amdgcn_global_load_lds(
      (const __attribute__((address_space(1))) unsigned int*)(g),
      (__attribute__((address_space(3))) unsigned int*)(l), 16, 0, 0);
}

// ---------------------------------------------------------------------------
// prep_all: one kernel, three phases by block range.
// ---------------------------------------------------------------------------
__global__ __launch_bounds__(256) void prep_all(
    const float* __restrict__ fa, const float* __restrict__ fb,
    const float* __restrict__ w10, const float* __restrict__ w11,
    const float* __restrict__ w12, const float* __restrict__ w20,
    const float* __restrict__ w21, const float* __restrict__ w22,
    unsigned short* __restrict__ X,
    unsigned short* __restrict__ W1T, unsigned short* __restrict__ W2T,
    unsigned short* __restrict__ VtKpad) {
  const int t = threadIdx.x;
  int id = blockIdx.x;
  if (id < 3072) {
    __shared__ float T[64][50];
    const int z = id / 1536; id -= z * 1536;
    const int ct = id % 12, img = id / 12;
    const float* feat = z ? fb : fa;
    const float* src = feat + (size_t)img * (CDIM * S49) + (size_t)ct * 64 * S49;
    for (int idx = t; idx < 64 * S49; idx += 256) {
      int cc = idx / S49, s = idx - cc * S49;
      T[cc][s] = src[cc * S49 + s];
    }
    __syncthreads();
    unsigned short* dst = X + (size_t)(z * 128 + img) * S49 * CDIM + ct * 64;
    for (int idx = t; idx < S49 * 64; idx += 256) {
      int s = idx >> 6, cc = idx & 63;
      dst[(size_t)s * CDIM + cc] = f2bf(T[cc][s]);
    }
  } else if (id < 5016) {
    __shared__ float T[32][33];
    id -= 3072;
    const float* src;
    unsigned short* dst;
    int C, ctile, rtile;
    if (id < 1728) {
      int wdx = id / 576, tid = id - wdx * 576;
      ctile = tid % 24; rtile = tid / 24;
      src = wdx == 0 ? w10 : (wdx == 1 ? w11 : w12);
      dst = W1T + (size_t)wdx * CDIM * CDIM;
      C = CDIM;
    } else {
      id -= 1728;
      int wdx = id / 72, tid = id - wdx * 72;
      ctile = tid % 3; rtile = tid / 3;
      src = wdx == 0 ? w20 : (wdx == 1 ? w21 : w22);
      dst = W2T + (size_t)wdx * INNER * CDIM;
      C = INNER;
    }
    const int c0 = ctile * 32, r0 = rtile * 32;
    for (int idx = t; idx < 1024; idx += 256) {
      int rr = idx >> 5, cc = idx & 31;
      T[rr][cc] = src[(size_t)(r0 + rr) * C + c0 + cc];
    }
    __syncthreads();
    for (int idx = t; idx < 1024; idx += 256) {
      int rr = idx >> 5, cc = idx & 31;
      dst[(size_t)(c0 + rr) * CDIM + r0 + cc] = f2bf(T[cc][rr]);
    }
  } else {
    id -= 5016;
    ushort4* p4 = (ushort4*)VtKpad;
    const ushort4 z = make_ushort4(0, 0, 0, 0);
#pragma unroll
    for (int i = 0; i < 32; i++)
      p4[(size_t)id * 8192 + i * 256 + t] = z;
  }
}

// ---------------------------------------------------------------------------
// gemm1_8p: H[wdx] = relu(X @ W1[wdx]). 256x256 tile, BK=64, 8-phase
// counted-vmcnt schedule (T3+T4), per guide §5 template.
//  - 8 waves (2M x 4N), wave tile 128x64, acc[8][4] = 128 VGPR.
//  - LDS 128KB: 2 bufs x 4 half-tiles (A0,A1,B0,B1 of 128x64 bf16, 16KB).
//    Linear gld16 dests; st_16x32-style swizzle via SOURCE-preswizzle
//    c ^= ((r>>3)&1)<<4, same involution applied on ds_read (rule #21).
//  - 4 phases per K-tile: {ds_read subtile | stage 1 half-tile ->
//    raw s_barrier (no drain) -> setprio+16 MFMA -> barrier}.
//    Stage schedule (tau,p): p0->A1(t+1) p1->B1(t+1) p2->B0(t+2) p3->A0(t+2);
//    every overwrite is >=1 closed barrier after its region's last read.
//  - vmcnt(4) once per K-tile (phase 3): tile tau+1 landed with 2 half-tiles
//    (4 loads) still in flight. Tail tau=10 drains vmcnt(0). Prologue: 6
//    half-tiles then vmcnt(4).
// ---------------------------------------------------------------------------
#define BARR() do { __builtin_amdgcn_sched_barrier(0); \
  __builtin_amdgcn_s_barrier(); __builtin_amdgcn_sched_barrier(0); } while (0)
#define STG(src, dhalf) do { \
  gld16((src), (dhalf) + t8); \
  gld16((src) + 32, (dhalf) + t8 + 4096); } while (0)
#define MFMA_QUAD(QM, QN) do { \
  __builtin_amdgcn_s_setprio(1); \
  _Pragma("unroll") \
  for (int mi = 0; mi < 4; ++mi) { \
    _Pragma("unroll") \
    for (int ni = 0; ni < 2; ++ni) { \
      _Pragma("unroll") \
      for (int ks = 0; ks < 2; ++ks) \
        acc[(QM)*4+mi][(QN)*2+ni] = __builtin_amdgcn_mfma_f32_16x16x32_bf16( \
            Af[mi*2+ks], Bf[((QN)*2+ni)*2+ks], acc[(QM)*4+mi][(QN)*2+ni], \
            0, 0, 0); \
    } \
  } \
  __builtin_amdgcn_s_setprio(0); } while (0)

__global__ __launch_bounds__(512, 2) void gemm1_8p(
    const unsigned short* __restrict__ X,
    const unsigned short* __restrict__ W1T,
    unsigned short* __restrict__ H, int wbase, int hsel) {
  __shared__ __align__(16) unsigned short L[2][4][8192];  // 128 KB
  const int t = threadIdx.x;
  const int lane = t & 63, w = t >> 6;
  const int lr = lane & 15, lq = lane >> 4;
  const int wm2 = w >> 2, wn4 = w & 3;
  // ---- bijective XCD swizzle over the full grid (m204 formula)
  const int gx = gridDim.x, gxy = gx * gridDim.y;
  const int nwg = gxy * gridDim.z;
  const int orig = blockIdx.x + gx * (blockIdx.y + gridDim.y * blockIdx.z);
  const int q8 = nwg >> 3, r8 = nwg & 7;
  const int xcd = orig & 7, rank = orig >> 3;
  const int logical = (xcd < r8 ? xcd * (q8 + 1) : r8 * (q8 + 1) + (xcd - r8) * q8) + rank;
  const int wdx_l = logical / gxy;
  const int rem = logical - wdx_l * gxy;
  const int M0 = (rem / gx) * 256, N0 = (rem % gx) * 256;
  const int wdx = wdx_l + wbase;
  const unsigned short* W1w = W1T + (size_t)wdx * CDIM * CDIM;
  unsigned short* Hw = H + (hsel ? (size_t)wdx * MROWS * CDIM : 0);

  // ---- staging source (per-thread): chunk t -> (r, swizzled col), kb=0/1
  const int rs = t >> 2;
  const int cs = ((t & 3) * 8) ^ (((rs >> 3) & 1) << 4);
  const int soff = rs * CDIM + cs;
  const unsigned short* pA0 = X + (size_t)M0 * CDIM + soff;
  const unsigned short* pA1 = pA0 + (size_t)128 * CDIM;
  const unsigned short* pB0 = W1w + (size_t)N0 * CDIM + soff;
  const unsigned short* pB1 = pB0 + (size_t)128 * CDIM;
  const int t8 = t * 8;

  // ---- ds_read base (same involution as the source preswizzle)
  const int rdbase = lr * 32 + ((lq * 8) ^ (((lr >> 3) & 1) << 4));
  const int bO = (wn4 & 1) * 2048;   // row offset within B half (64 rows)

  const f32x4 z4 = {0.f, 0.f, 0.f, 0.f};
  f32x4 acc[8][4];
#pragma unroll
  for (int i = 0; i < 8; ++i)
#pragma unroll
    for (int j = 0; j < 4; ++j) acc[i][j] = z4;
  bf16x8 Af[8], Bf[8];

  // ---- prologue: tile0 {B0,A0,A1,B1}, tile1 {B0,A0}; land tile0.
  STG(pB0, &L[0][2][0]);
  STG(pA0, &L[0][0][0]);
  STG(pA1, &L[0][1][0]);
  STG(pB1, &L[0][3][0]);
  STG(pB0 + 64, &L[1][2][0]);
  STG(pA0 + 64, &L[1][0][0]);
  asm volatile("s_waitcnt vmcnt(4)" ::: "memory");
  BARR();

  for (int tau = 0; tau < 12; ++tau) {
    const int buf = tau & 1;
    const unsigned short* LA = &L[buf][wm2][0];
    const unsigned short* LB = &L[buf][2 + (wn4 >> 1)][0];
    // ---- phase 0: read A(qm0) + B(qn0); stage A1(tau+1)
#pragma unroll
    for (int mf = 0; mf < 4; ++mf)
#pragma unroll
      for (int ks = 0; ks < 2; ++ks)
        Af[mf * 2 + ks] = *(const bf16x8*)(LA + ks * 4096 + mf * 512 + rdbase);
#pragma unroll
    for (int nf = 0; nf < 2; ++nf)
#pragma unroll
      for (int ks = 0; ks < 2; ++ks)
        Bf[nf * 2 + ks] = *(const bf16x8*)(LB + ks * 4096 + bO + nf * 512 + rdbase);
    if (tau + 1 < 12) STG(pA1 + (tau + 1) * 64, &L[(tau + 1) & 1][1][0]);
    BARR();
    MFMA_QUAD(0, 0);
    BARR();
    // ---- phase 1: read B(qn1); stage B1(tau+1)
#pragma unroll
    for (int nf = 2; nf < 4; ++nf)
#pragma unroll
      for (int ks = 0; ks < 2; ++ks)
        Bf[nf * 2 + ks] = *(const bf16x8*)(LB + ks * 4096 + bO + nf * 512 + rdbase);
    if (tau + 1 < 12) STG(pB1 + (tau + 1) * 64, &L[(tau + 1) & 1][3][0]);
    BARR();
    MFMA_QUAD(0, 1);
    BARR();
    // ---- phase 2: read A(qm1); stage B0(tau+2) (same buf, B-region: done)
#pragma unroll
    for (int mf = 4; mf < 8; ++mf)
#pragma unroll
      for (int ks = 0; ks < 2; ++ks)
        Af[(mf - 4) * 2 + ks] = *(const bf16x8*)(LA + ks * 4096 + mf * 512 + rdbase);
    if (tau + 2 < 12) STG(pB0 + (tau + 2) * 64, &L[buf][2][0]);
    BARR();
    MFMA_QUAD(1, 0);
    BARR();
    // ---- phase 3: stage A0(tau+2); counted vmcnt lands tile tau+1
    if (tau + 2 < 12) STG(pA0 + (tau + 2) * 64, &L[buf][0][0]);
    if (tau < 10) {
      asm volatile("s_waitcnt vmcnt(4)" ::: "memory");
    } else if (tau == 10) {
      asm volatile("s_waitcnt vmcnt(0)" ::: "memory");
    }
    BARR();
    MFMA_QUAD(1, 1);
    BARR();
  }
  // ---- epilogue: m = M0 + wm2*128 + mf*16 + lq*4 + r; n = N0 + wn4*64 + nf*16 + lr
#pragma unroll
  for (int mf = 0; mf < 8; ++mf)
#pragma unroll
    for (int nf = 0; nf < 4; ++nf)
#pragma unroll
      for (int r = 0; r < 4; ++r) {
        int m = M0 + wm2 * 128 + mf * 16 + lq * 4 + r;
        int n = N0 + wn4 * 64 + nf * 16 + lr;
        Hw[(size_t)m * CDIM + n] = f2bf(fmaxf(acc[mf][nf][r], 0.f));
      }
}

// ---------------------------------------------------------------------------
// gemm2b5: O = H[wdx] @ W2[wdx]. Verified R9 (source-preswizzled gld16,
// BK=128, 512 thr / 8 waves, LDS 40960 = 4 blocks/CU).
// ---------------------------------------------------------------------------
__global__ __launch_bounds__(512) void gemm2b5(const unsigned short* __restrict__ H,
                                               const unsigned short* __restrict__ W2T,
                                               unsigned short* __restrict__ QKV,
                                               unsigned short* __restrict__ Kpad,
                                               unsigned short* __restrict__ Vt,
                                               float* __restrict__ vnorm,
                                               int wbase, int hsel) {
  __shared__ __align__(16) unsigned short As[64 * 128];   // 16 KB
  __shared__ __align__(16) unsigned short Bs[96 * 128];   // 24 KB
  const int t = threadIdx.x;
  const int lane = t & 63, w = t >> 6;
  const int lr = lane & 15, lq = lane >> 4;
  const int wm = w & 3, we = w >> 2;      // m quarter (16 rows), e half (48)
  const int m0 = blockIdx.x * 64;
  const int wdx = blockIdx.y + wbase;
  const unsigned short* Hw = H + (hsel ? (size_t)wdx * MROWS * CDIM : 0);
  const unsigned short* W2w = W2T + (size_t)wdx * INNER * CDIM;
  const f32x4 z4 = {0.f, 0.f, 0.f, 0.f};
  f32x4 acc[3] = {z4, z4, z4};

  for (int k0 = 0; k0 < CDIM; k0 += 128) {
    __syncthreads();
#pragma unroll
    for (int j = 0; j < 2; j++) {
      int l = t + j * 512;
      int row = l >> 4, ch = l & 15;
      gld16(Hw + (size_t)(m0 + row) * CDIM + k0 + (ch ^ (row & 7)) * 8, As + l * 8);
    }
#pragma unroll
    for (int j = 0; j < 3; j++) {
      int l = t + j * 512;
      int row = l >> 4, ch = l & 15;
      gld16(W2w + (size_t)row * CDIM + k0 + (ch ^ (row & 7)) * 8, Bs + l * 8);
    }
    __syncthreads();
#pragma unroll
    for (int kk = 0; kk < 4; kk++) {
      int ca = (kk * 4 + lq) ^ (lr & 7);
      bf16x8 a = *(const bf16x8*)(As + (wm * 16 + lr) * 128 + ca * 8);
#pragma unroll
      for (int et = 0; et < 3; et++) {
        bf16x8 b = *(const bf16x8*)(Bs + (we * 48 + et * 16 + lr) * 128 + ca * 8);
        acc[et] = __builtin_amdgcn_mfma_f32_16x16x32_bf16(a, b, acc[et], 0, 0, 0);
      }
    }
  }
  float nsq[4] = {0.f, 0.f, 0.f, 0.f};
#pragma unroll
  for (int et = 0; et < 3; et++)
#pragma unroll
    for (int r = 0; r < 4; r++) {
      int m = m0 + wm * 16 + lq * 4 + r;
      int e = we * 48 + et * 16 + lr;
      float v = acc[et][r];
      int img = m / 49, s = m - img * 49;
      if (wdx == 0) {
        QKV[(size_t)m * INNER + e] = f2bf(v * SCALE_EXP2);
      } else if (wdx == 1) {
        Kpad[(size_t)(img * 64 + s) * INNER + e] = f2bf(v);
      } else {
        QKV[(size_t)(2 * MROWS + m) * INNER + e] = f2bf(v);
        Vt[(size_t)img * (INNER * 64) + e * 64 + s] = f2bf(v);
        nsq[r] += v * v;
      }
    }
  if (wdx == 2) {
    __syncthreads();
    float (*nsqp)[64] = (float (*)[64])As;
#pragma unroll
    for (int r = 0; r < 4; r++) {
      float p = nsq[r];
      p += __shfl_xor(p, 1, 16);
      p += __shfl_xor(p, 2, 16);
      p += __shfl_xor(p, 4, 16);
      p += __shfl_xor(p, 8, 16);
      if (lr == 0) nsqp[we][wm * 16 + lq * 4 + r] = p;
    }
    __syncthreads();
    if (t < 64) vnorm[m0 + t] = sqrtf(nsqp[0][t] + nsqp[1][t]);
  }
}

// ---------------------------------------------------------------------------
// attn11 (verified ~89us): K single-buffered, Vt async-staged to LDS,
// 2 barriers/fi, LDS 40960B = 4 blocks/CU, grid 1568, setprio on MFMA.
// ---------------------------------------------------------------------------
__global__ __launch_bounds__(256) void attn11(const unsigned short* __restrict__ Qp,
                                              const unsigned short* __restrict__ Kpad,
                                              const unsigned short* __restrict__ V,
                                              const unsigned short* __restrict__ Vt,
                                              const float* __restrict__ vnorm,
                                              float* __restrict__ cosbuf) {
  __shared__ __align__(16) unsigned short Ks[64 * INNER];      // 12 KB
  __shared__ __align__(16) unsigned short VtS[INNER * 64];     // 12 KB
  __shared__ __align__(16) unsigned short Ps[4][32 * 64];      // 16 KB

  const int t = threadIdx.x;
  const int lane = t & 63, w = t >> 6;
  const int lr = lane & 15, lq = lane >> 4;
  const f32x4 z4 = {0.f, 0.f, 0.f, 0.f};

  int bx = blockIdx.x;
  const int dir = bx / 784; bx -= dir * 784;     // 784 = 49 chunks * 16 fgroups
  const int chunk = bx >> 4, fg = bx & 15;
  const int r0 = chunk * 128;
  const int qbase = dir * NSIDE;

  int goK[3], goV[3], lo[3];
#pragma unroll
  for (int j = 0; j < 3; j++) {
    int l = (w * 3 + j) * 64 + lane;
    lo[j] = l * 8;
    int rK = l / 12, scK = l - rK * 12;
    int ccK = scK - ((rK >> 1) & 7); if (ccK < 0) ccK += 12;
    goK[j] = rK * INNER + ccK * 8;
    int rV = l >> 3, scV = l & 7;
    int ccV = (scV - (rV & 7)) & 7;
    goV[j] = rV * 64 + ccV * 8;
  }
  int rdK[3], rdV[2];
#pragma unroll
  for (int ks = 0; ks < 3; ks++) {
    int sc = (ks * 4 + lq + ((lr >> 1) & 7)) % 12;
    rdK[ks] = lr * INNER + sc * 8;
  }
#pragma unroll
  for (int ks = 0; ks < 2; ks++) {
    int sc = (ks * 4 + lq + (lr & 7)) & 7;
    rdV[ks] = lr * 64 + sc * 8;
  }

  bf16x8 qf[2][3];
#pragma unroll
  for (int qt = 0; qt < 2; qt++) {
    const int qrow = qbase + r0 + w * 32 + qt * 16 + lr;
#pragma unroll
    for (int ks = 0; ks < 3; ks++)
      qf[qt][ks] = *(const bf16x8*)(Qp + (size_t)qrow * INNER + ks * 32 + lq * 8);
  }
  float rv[2][6][4], invvn[2];
#pragma unroll
  for (int qt = 0; qt < 2; qt++) {
    const int qrow = qbase + r0 + w * 32 + qt * 16 + lr;
    invvn[qt] = 1.f / fmaxf(vnorm[qrow], 1e-8f);
#pragma unroll
    for (int et = 0; et < 6; et++) {
      ushort4 u = *(const ushort4*)(V + (size_t)qrow * INNER + et * 16 + lq * 4);
      rv[qt][et][0] = bf2f(u.x); rv[qt][et][1] = bf2f(u.y);
      rv[qt][et][2] = bf2f(u.z); rv[qt][et][3] = bf2f(u.w);
    }
  }

  unsigned short* Pw = &Ps[w][0];
  const int kimg0 = (dir == 0 ? 128 : 0) + fg * 8;
  {
    const unsigned short* kg = Kpad + (size_t)kimg0 * (64 * INNER);
#pragma unroll
    for (int j = 0; j < 3; j++) gld16(kg + goK[j], Ks + lo[j]);
  }
  for (int fi = 0; fi < 8; fi++) {
    const int f = fg * 8 + fi;
    __syncthreads();   // (1) drains K[fi]; prev PV done by all waves
    {
      const unsigned short* vg = Vt + (size_t)(kimg0 + fi) * (INNER * 64);
#pragma unroll
      for (int j = 0; j < 3; j++) gld16(vg + goV[j], VtS + lo[j]);
    }
    f32x4 s4[2][4] = {{z4, z4, z4, z4}, {z4, z4, z4, z4}};
    __builtin_amdgcn_s_setprio(1);
#pragma unroll
    for (int ks = 0; ks < 3; ks++) {
#pragma unroll
      for (int kt = 0; kt < 4; kt++) {
        bf16x8 a = *(const bf16x8*)(Ks + kt * (16 * INNER) + rdK[ks]);
        s4[0][kt] = __builtin_amdgcn_mfma_f32_16x16x32_bf16(a, qf[0][ks], s4[0][kt], 0, 0, 0);
        s4[1][kt] = __builtin_amdgcn_mfma_f32_16x16x32_bf16(a, qf[1][ks], s4[1][kt], 0, 0, 0);
      }
    }
    __builtin_amdgcn_s_setprio(0);
#pragma unroll
    for (int qt = 0; qt < 2; qt++)
#pragma unroll
      for (int kt = 0; kt < 4; kt++) {
        float e0 = __builtin_exp2f(s4[qt][kt][0]);
        float e1 = __builtin_exp2f(s4[qt][kt][1]);
        float e2 = __builtin_exp2f(s4[qt][kt][2]);
        float e3 = __builtin_exp2f(s4[qt][kt][3]);
        uint2 pk = make_uint2(pack_bf16_rn(e0, e1), pack_bf16_rn(e2, e3));
        int row = qt * 16 + lr;
        int ch = (2 * kt + (lq >> 1)) ^ (row & 7);
        *(uint2*)(Pw + row * 64 + ch * 8 + (lq & 1) * 4) = pk;
      }
    __syncthreads();   // (2) drains Vt[fi]; all waves' K reads done
    if (fi < 7) {
      const unsigned short* kg = Kpad + (size_t)(kimg0 + fi + 1) * (64 * INNER);
#pragma unroll
      for (int j = 0; j < 3; j++) gld16(kg + goK[j], Ks + lo[j]);
    }
    f32x4 pv[2][6] = {{z4, z4, z4, z4, z4, z4}, {z4, z4, z4, z4, z4, z4}};
    __builtin_amdgcn_s_setprio(1);
#pragma unroll
    for (int ks = 0; ks < 2; ks++) {
      int row0 = 0 * 16 + lr, row1 = 1 * 16 + lr;
      int ch0 = ((ks * 4 + lq) ^ (row0 & 7));
      int ch1 = ((ks * 4 + lq) ^ (row1 & 7));
      bf16x8 b0 = *(const bf16x8*)(Pw + row0 * 64 + ch0 * 8);
      bf16x8 b1 = *(const bf16x8*)(Pw + row1 * 64 + ch1 * 8);
#pragma unroll
      for (int et = 0; et < 6; et++) {
        bf16x8 a = *(const bf16x8*)(VtS + et * (16 * 64) + rdV[ks]);
        pv[0][et] = __builtin_amdgcn_mfma_f32_16x16x32_bf16(a, b0, pv[0][et], 0, 0, 0);
        pv[1][et] = __builtin_amdgcn_mfma_f32_16x16x32_bf16(a, b1, pv[1][et], 0, 0, 0);
      }
    }
    __builtin_amdgcn_s_setprio(0);
#pragma unroll
    for (int qt = 0; qt < 2; qt++) {
      float d = 0.f, nn = 0.f;
#pragma unroll
      for (int et = 0; et < 6; et++)
#pragma unroll
        for (int r = 0; r < 4; r++) {
          float al = pv[qt][et][r];
          d += al * rv[qt][et][r];
          nn += al * al;
        }
      d += __shfl_xor(d, 16, 64);  d += __shfl_xor(d, 32, 64);
      nn += __shfl_xor(nn, 16, 64); nn += __shfl_xor(nn, 32, 64);
      if (lane < 16) {
        float cv = d * __frsqrt_rn(fmaxf(nn, 1e-40f)) * invvn[qt];
        cosbuf[(size_t)(dir * 128 + f) * NSIDE + r0 + w * 32 + qt * 16 + lr] = cv;
      }
    }
  }
}

// ---------------------------------------------------------------------------
// reduce_out: out[bb*128+aa] = (sum_q cos0[bb][aa*49+q] + cos1[aa][bb*49+q])/49
// ---------------------------------------------------------------------------
__global__ __launch_bounds__(256) void reduce_out(const float* __restrict__ cosbuf,
                                                  float* __restrict__ out) {
  const int t = threadIdx.x, lane = t & 63, wv = t >> 6;
  const int pair = blockIdx.x * 4 + wv;
  const int bb = pair >> 7, aa = pair & 127;
  float v = 0.f;
  if (lane < S49) {
    v  = cosbuf[(size_t)bb * NSIDE + aa * S49 + lane];
    v += cosbuf[(size_t)(128 + aa) * NSIDE + bb * S49 + lane];
  }
  for (int m = 1; m < 64; m <<= 1) v += __shfl_xor(v, m, 64);
  if (lane == 0) out[pair] = v * (1.f / 49.f);
}

// ---------------------------------------------------------------------------
extern "C" void kernel_launch(void* const* d_in, const int* in_sizes, int n_in,
                              void* d_out, int out_size, void* d_ws, size_t ws_size,
                              hipStream_t stream) {
  const float* fa  = (const float*)d_in[0];
  const float* fb  = (const float*)d_in[1];
  const float* W1[3] = {(const float*)d_in[2], (const float*)d_in[4], (const float*)d_in[6]};
  const float* W2[3] = {(const float*)d_in[3], (const float*)d_in[5], (const float*)d_in[7]};
  float* out = (float*)d_out;

  unsigned short* p = (unsigned short*)d_ws;
  unsigned short* Xbf = p;                 p += (size_t)MROWS * CDIM;      // 19.3 MB
  unsigned short* W1T = p;                 p += (size_t)3 * CDIM * CDIM;   // 3.5 MB
  unsigned short* W2T = p;                 p += (size_t)3 * INNER * CDIM;  // 0.44 MB
  unsigned short* QKV = p;                 p += (size_t)3 * MROWS * INNER; // 7.2 MB
  unsigned short* Vt  = p;                 p += (size_t)256 * INNER * 64;  // 3.1 MB
  unsigned short* Kpad = p;                p += (size_t)256 * 64 * INNER;  // 3.1 MB (adjacent to Vt!)
  float* vnorm = (float*)p;                p += (size_t)MROWS * 2;         // 50 KB
  float* cosbuf = (float*)p;               p += (size_t)256 * NSIDE * 2;   // 6.4 MB
  unsigned short* H = p;                   p += (size_t)3 * MROWS * CDIM;  // 57.8 MB (batched)
  const size_t need_batched = (size_t)(p - (unsigned short*)d_ws) * 2;
  const int batched = ws_size >= need_batched;

  prep_all<<<dim3(5112), 256, 0, stream>>>(fa, fb, W1[0], W1[1], W1[2],
                                           W2[0], W2[1], W2[2],
                                           Xbf, W1T, W2T, Vt /* VtKpad span */);
  if (batched) {
    gemm1_8p<<<dim3(CDIM / 256, MROWS / 256, 3), 512, 0, stream>>>(Xbf, W1T, H, 0, 1);
    gemm2b5<<<dim3(MROWS / 64, 3), 512, 0, stream>>>(H, W2T, QKV, Kpad, Vt, vnorm, 0, 1);
  } else {
    for (int wdx = 0; wdx < 3; wdx++) {
      gemm1_8p<<<dim3(CDIM / 256, MROWS / 256, 1), 512, 0, stream>>>(Xbf, W1T, H, wdx, 0);
      gemm2b5<<<dim3(MROWS / 64, 1), 512, 0, stream>>>(H, W2T, QKV, Kpad, Vt, vnorm, wdx, 0);
    }
  }
  attn11<<<dim3(2 * 784), 256, 0, stream>>>(
      QKV, Kpad, QKV + (size_t)2 * MROWS * INNER, Vt, vnorm, cosbuf);
  reduce_out<<<dim3(4096), 256, 0, stream>>>(cosbuf, out);
}

// Round 11
// 252.713 us; speedup vs baseline: 1.1947x; 1.0252x over previous
//
#include <hip/hip_runtime.h>
#include <hip/hip_bf16.h>
#include <math.h>

typedef __attribute__((ext_vector_type(8))) short bf16x8;
typedef __attribute__((ext_vector_type(4))) float f32x4;
typedef __attribute__((ext_vector_type(2))) float f32x2;

#define MROWS 12544      // (128+128)*49
#define CDIM 768
#define INNER 96
#define S49 49
#define NSIDE 6272       // 128*49 rows per side
#define SCALE 0.10206207261596577f
// SCALE * log2(e): Q prescale so attn can use exp2 directly
#define SCALE_EXP2 ((float)(0.10206207261596577 * 1.4426950408889634))

__device__ __forceinline__ unsigned short f2bf(float f) {
  union { float f; unsigned u; } v; v.f = f;
  unsigned u = v.u;
  return (unsigned short)((u + 0x7fffu + ((u >> 16) & 1u)) >> 16);
}
__device__ __forceinline__ float bf2f(unsigned short h) {
  union { unsigned u; float f; } v; v.u = ((unsigned)h) << 16;
  return v.f;
}
// pack two floats to bf16x2 (round-to-nearest-ish): low=a, high=b
__device__ __forceinline__ unsigned pack_bf16_rn(float a, float b) {
  union { float f; unsigned u; } ua, ub; ua.f = a; ub.f = b;
  return __builtin_amdgcn_perm(ub.u + 0x8000u, ua.u + 0x8000u, 0x07060302u);
}

// async global->LDS, 16B per lane. Dest must be wave-uniform base + lane*16.
__device__ __forceinline__ void gld16(const unsigned short* g, unsigned short* l) {
  __builtin_amdgcn_global_load_lds(
      (const __attribute__((address_space(1))) unsigned int*)(g),
      (__attribute__((address_space(3))) unsigned int*)(l), 16, 0, 0);
}

// ---------------------------------------------------------------------------
// prep_all: one kernel, three phases by block range.
// ---------------------------------------------------------------------------
__global__ __launch_bounds__(256) void prep_all(
    const float* __restrict__ fa, const float* __restrict__ fb,
    const float* __restrict__ w10, const float* __restrict__ w11,
    const float* __restrict__ w12, const float* __restrict__ w20,
    const float* __restrict__ w21, const float* __restrict__ w22,
    unsigned short* __restrict__ X,
    unsigned short* __restrict__ W1T, unsigned short* __restrict__ W2T,
    unsigned short* __restrict__ VtKpad) {
  const int t = threadIdx.x;
  int id = blockIdx.x;
  if (id < 3072) {
    __shared__ float T[64][50];
    const int z = id / 1536; id -= z * 1536;
    const int ct = id % 12, img = id / 12;
    const float* feat = z ? fb : fa;
    const float* src = feat + (size_t)img * (CDIM * S49) + (size_t)ct * 64 * S49;
    for (int idx = t; idx < 64 * S49; idx += 256) {
      int cc = idx / S49, s = idx - cc * S49;
      T[cc][s] = src[cc * S49 + s];
    }
    __syncthreads();
    unsigned short* dst = X + (size_t)(z * 128 + img) * S49 * CDIM + ct * 64;
    for (int idx = t; idx < S49 * 64; idx += 256) {
      int s = idx >> 6, cc = idx & 63;
      dst[(size_t)s * CDIM + cc] = f2bf(T[cc][s]);
    }
  } else if (id < 5016) {
    __shared__ float T[32][33];
    id -= 3072;
    const float* src;
    unsigned short* dst;
    int C, ctile, rtile;
    if (id < 1728) {
      int wdx = id / 576, tid = id - wdx * 576;
      ctile = tid % 24; rtile = tid / 24;
      src = wdx == 0 ? w10 : (wdx == 1 ? w11 : w12);
      dst = W1T + (size_t)wdx * CDIM * CDIM;
      C = CDIM;
    } else {
      id -= 1728;
      int wdx = id / 72, tid = id - wdx * 72;
      ctile = tid % 3; rtile = tid / 3;
      src = wdx == 0 ? w20 : (wdx == 1 ? w21 : w22);
      dst = W2T + (size_t)wdx * INNER * CDIM;
      C = INNER;
    }
    const int c0 = ctile * 32, r0 = rtile * 32;
    for (int idx = t; idx < 1024; idx += 256) {
      int rr = idx >> 5, cc = idx & 31;
      T[rr][cc] = src[(size_t)(r0 + rr) * C + c0 + cc];
    }
    __syncthreads();
    for (int idx = t; idx < 1024; idx += 256) {
      int rr = idx >> 5, cc = idx & 31;
      dst[(size_t)(c0 + rr) * CDIM + r0 + cc] = f2bf(T[cc][rr]);
    }
  } else {
    id -= 5016;
    ushort4* p4 = (ushort4*)VtKpad;
    const ushort4 z = make_ushort4(0, 0, 0, 0);
#pragma unroll
    for (int i = 0; i < 32; i++)
      p4[(size_t)id * 8192 + i * 256 + t] = z;
  }
}

// ---------------------------------------------------------------------------
// gemm1_8p: H[wdx] = relu(X @ W1[wdx]). 256x256 tile, BK=64, 8-phase
// counted-vmcnt schedule (T3+T4). Verified WIN R10 (-19us).
// ---------------------------------------------------------------------------
#define BARR() do { __builtin_amdgcn_sched_barrier(0); \
  __builtin_amdgcn_s_barrier(); __builtin_amdgcn_sched_barrier(0); } while (0)
#define STG(src, dhalf) do { \
  gld16((src), (dhalf) + t8); \
  gld16((src) + 32, (dhalf) + t8 + 4096); } while (0)
#define MFMA_QUAD(QM, QN) do { \
  __builtin_amdgcn_s_setprio(1); \
  _Pragma("unroll") \
  for (int mi = 0; mi < 4; ++mi) { \
    _Pragma("unroll") \
    for (int ni = 0; ni < 2; ++ni) { \
      _Pragma("unroll") \
      for (int ks = 0; ks < 2; ++ks) \
        acc[(QM)*4+mi][(QN)*2+ni] = __builtin_amdgcn_mfma_f32_16x16x32_bf16( \
            Af[mi*2+ks], Bf[((QN)*2+ni)*2+ks], acc[(QM)*4+mi][(QN)*2+ni], \
            0, 0, 0); \
    } \
  } \
  __builtin_amdgcn_s_setprio(0); } while (0)

__global__ __launch_bounds__(512, 2) void gemm1_8p(
    const unsigned short* __restrict__ X,
    const unsigned short* __restrict__ W1T,
    unsigned short* __restrict__ H, int wbase, int hsel) {
  __shared__ __align__(16) unsigned short L[2][4][8192];  // 128 KB
  const int t = threadIdx.x;
  const int lane = t & 63, w = t >> 6;
  const int lr = lane & 15, lq = lane >> 4;
  const int wm2 = w >> 2, wn4 = w & 3;
  // ---- bijective XCD swizzle over the full grid (m204 formula)
  const int gx = gridDim.x, gxy = gx * gridDim.y;
  const int nwg = gxy * gridDim.z;
  const int orig = blockIdx.x + gx * (blockIdx.y + gridDim.y * blockIdx.z);
  const int q8 = nwg >> 3, r8 = nwg & 7;
  const int xcd = orig & 7, rank = orig >> 3;
  const int logical = (xcd < r8 ? xcd * (q8 + 1) : r8 * (q8 + 1) + (xcd - r8) * q8) + rank;
  const int wdx_l = logical / gxy;
  const int rem = logical - wdx_l * gxy;
  const int M0 = (rem / gx) * 256, N0 = (rem % gx) * 256;
  const int wdx = wdx_l + wbase;
  const unsigned short* W1w = W1T + (size_t)wdx * CDIM * CDIM;
  unsigned short* Hw = H + (hsel ? (size_t)wdx * MROWS * CDIM : 0);

  // ---- staging source (per-thread): chunk t -> (r, swizzled col), kb=0/1
  const int rs = t >> 2;
  const int cs = ((t & 3) * 8) ^ (((rs >> 3) & 1) << 4);
  const int soff = rs * CDIM + cs;
  const unsigned short* pA0 = X + (size_t)M0 * CDIM + soff;
  const unsigned short* pA1 = pA0 + (size_t)128 * CDIM;
  const unsigned short* pB0 = W1w + (size_t)N0 * CDIM + soff;
  const unsigned short* pB1 = pB0 + (size_t)128 * CDIM;
  const int t8 = t * 8;

  // ---- ds_read base (same involution as the source preswizzle)
  const int rdbase = lr * 32 + ((lq * 8) ^ (((lr >> 3) & 1) << 4));
  const int bO = (wn4 & 1) * 2048;   // row offset within B half (64 rows)

  const f32x4 z4 = {0.f, 0.f, 0.f, 0.f};
  f32x4 acc[8][4];
#pragma unroll
  for (int i = 0; i < 8; ++i)
#pragma unroll
    for (int j = 0; j < 4; ++j) acc[i][j] = z4;
  bf16x8 Af[8], Bf[8];

  // ---- prologue: tile0 {B0,A0,A1,B1}, tile1 {B0,A0}; land tile0.
  STG(pB0, &L[0][2][0]);
  STG(pA0, &L[0][0][0]);
  STG(pA1, &L[0][1][0]);
  STG(pB1, &L[0][3][0]);
  STG(pB0 + 64, &L[1][2][0]);
  STG(pA0 + 64, &L[1][0][0]);
  asm volatile("s_waitcnt vmcnt(4)" ::: "memory");
  BARR();

  for (int tau = 0; tau < 12; ++tau) {
    const int buf = tau & 1;
    const unsigned short* LA = &L[buf][wm2][0];
    const unsigned short* LB = &L[buf][2 + (wn4 >> 1)][0];
    // ---- phase 0: read A(qm0) + B(qn0); stage A1(tau+1)
#pragma unroll
    for (int mf = 0; mf < 4; ++mf)
#pragma unroll
      for (int ks = 0; ks < 2; ++ks)
        Af[mf * 2 + ks] = *(const bf16x8*)(LA + ks * 4096 + mf * 512 + rdbase);
#pragma unroll
    for (int nf = 0; nf < 2; ++nf)
#pragma unroll
      for (int ks = 0; ks < 2; ++ks)
        Bf[nf * 2 + ks] = *(const bf16x8*)(LB + ks * 4096 + bO + nf * 512 + rdbase);
    if (tau + 1 < 12) STG(pA1 + (tau + 1) * 64, &L[(tau + 1) & 1][1][0]);
    BARR();
    MFMA_QUAD(0, 0);
    BARR();
    // ---- phase 1: read B(qn1); stage B1(tau+1)
#pragma unroll
    for (int nf = 2; nf < 4; ++nf)
#pragma unroll
      for (int ks = 0; ks < 2; ++ks)
        Bf[nf * 2 + ks] = *(const bf16x8*)(LB + ks * 4096 + bO + nf * 512 + rdbase);
    if (tau + 1 < 12) STG(pB1 + (tau + 1) * 64, &L[(tau + 1) & 1][3][0]);
    BARR();
    MFMA_QUAD(0, 1);
    BARR();
    // ---- phase 2: read A(qm1); stage B0(tau+2) (same buf, B-region: done)
#pragma unroll
    for (int mf = 4; mf < 8; ++mf)
#pragma unroll
      for (int ks = 0; ks < 2; ++ks)
        Af[(mf - 4) * 2 + ks] = *(const bf16x8*)(LA + ks * 4096 + mf * 512 + rdbase);
    if (tau + 2 < 12) STG(pB0 + (tau + 2) * 64, &L[buf][2][0]);
    BARR();
    MFMA_QUAD(1, 0);
    BARR();
    // ---- phase 3: stage A0(tau+2); counted vmcnt lands tile tau+1
    if (tau + 2 < 12) STG(pA0 + (tau + 2) * 64, &L[buf][0][0]);
    if (tau < 10) {
      asm volatile("s_waitcnt vmcnt(4)" ::: "memory");
    } else if (tau == 10) {
      asm volatile("s_waitcnt vmcnt(0)" ::: "memory");
    }
    BARR();
    MFMA_QUAD(1, 1);
    BARR();
  }
  // ---- epilogue: m = M0 + wm2*128 + mf*16 + lq*4 + r; n = N0 + wn4*64 + nf*16 + lr
#pragma unroll
  for (int mf = 0; mf < 8; ++mf)
#pragma unroll
    for (int nf = 0; nf < 4; ++nf)
#pragma unroll
      for (int r = 0; r < 4; ++r) {
        int m = M0 + wm2 * 128 + mf * 16 + lq * 4 + r;
        int n = N0 + wn4 * 64 + nf * 16 + lr;
        Hw[(size_t)m * CDIM + n] = f2bf(fmaxf(acc[mf][nf][r], 0.f));
      }
}

// ---------------------------------------------------------------------------
// gemm2b5: O = H[wdx] @ W2[wdx]. Verified R9 (source-preswizzled gld16,
// BK=128, 512 thr / 8 waves, LDS 40960 = 4 blocks/CU).
// ---------------------------------------------------------------------------
__global__ __launch_bounds__(512) void gemm2b5(const unsigned short* __restrict__ H,
                                               const unsigned short* __restrict__ W2T,
                                               unsigned short* __restrict__ QKV,
                                               unsigned short* __restrict__ Kpad,
                                               unsigned short* __restrict__ Vt,
                                               float* __restrict__ vnorm,
                                               int wbase, int hsel) {
  __shared__ __align__(16) unsigned short As[64 * 128];   // 16 KB
  __shared__ __align__(16) unsigned short Bs[96 * 128];   // 24 KB
  const int t = threadIdx.x;
  const int lane = t & 63, w = t >> 6;
  const int lr = lane & 15, lq = lane >> 4;
  const int wm = w & 3, we = w >> 2;      // m quarter (16 rows), e half (48)
  const int m0 = blockIdx.x * 64;
  const int wdx = blockIdx.y + wbase;
  const unsigned short* Hw = H + (hsel ? (size_t)wdx * MROWS * CDIM : 0);
  const unsigned short* W2w = W2T + (size_t)wdx * INNER * CDIM;
  const f32x4 z4 = {0.f, 0.f, 0.f, 0.f};
  f32x4 acc[3] = {z4, z4, z4};

  for (int k0 = 0; k0 < CDIM; k0 += 128) {
    __syncthreads();
#pragma unroll
    for (int j = 0; j < 2; j++) {
      int l = t + j * 512;
      int row = l >> 4, ch = l & 15;
      gld16(Hw + (size_t)(m0 + row) * CDIM + k0 + (ch ^ (row & 7)) * 8, As + l * 8);
    }
#pragma unroll
    for (int j = 0; j < 3; j++) {
      int l = t + j * 512;
      int row = l >> 4, ch = l & 15;
      gld16(W2w + (size_t)row * CDIM + k0 + (ch ^ (row & 7)) * 8, Bs + l * 8);
    }
    __syncthreads();
#pragma unroll
    for (int kk = 0; kk < 4; kk++) {
      int ca = (kk * 4 + lq) ^ (lr & 7);
      bf16x8 a = *(const bf16x8*)(As + (wm * 16 + lr) * 128 + ca * 8);
#pragma unroll
      for (int et = 0; et < 3; et++) {
        bf16x8 b = *(const bf16x8*)(Bs + (we * 48 + et * 16 + lr) * 128 + ca * 8);
        acc[et] = __builtin_amdgcn_mfma_f32_16x16x32_bf16(a, b, acc[et], 0, 0, 0);
      }
    }
  }
  float nsq[4] = {0.f, 0.f, 0.f, 0.f};
#pragma unroll
  for (int et = 0; et < 3; et++)
#pragma unroll
    for (int r = 0; r < 4; r++) {
      int m = m0 + wm * 16 + lq * 4 + r;
      int e = we * 48 + et * 16 + lr;
      float v = acc[et][r];
      int img = m / 49, s = m - img * 49;
      if (wdx == 0) {
        QKV[(size_t)m * INNER + e] = f2bf(v * SCALE_EXP2);
      } else if (wdx == 1) {
        Kpad[(size_t)(img * 64 + s) * INNER + e] = f2bf(v);
      } else {
        QKV[(size_t)(2 * MROWS + m) * INNER + e] = f2bf(v);
        Vt[(size_t)img * (INNER * 64) + e * 64 + s] = f2bf(v);
        nsq[r] += v * v;
      }
    }
  if (wdx == 2) {
    __syncthreads();
    float (*nsqp)[64] = (float (*)[64])As;
#pragma unroll
    for (int r = 0; r < 4; r++) {
      float p = nsq[r];
      p += __shfl_xor(p, 1, 16);
      p += __shfl_xor(p, 2, 16);
      p += __shfl_xor(p, 4, 16);
      p += __shfl_xor(p, 8, 16);
      if (lr == 0) nsqp[we][wm * 16 + lq * 4 + r] = p;
    }
    __syncthreads();
    if (t < 64) vnorm[m0 + t] = sqrtf(nsqp[0][t] + nsqp[1][t]);
  }
}

// ---------------------------------------------------------------------------
// attn13: attn11 (verified ~90us) + VALU cuts (R11):
//  - cosine epilogue via v_pk_fma_f32 (packed f32): 96 FMA -> 48 pk_fma,
//    accumulator chains split 2-way (halves serial dep latency).
//  - P-pack via v_cvt_pk_bf16_f32 (1 inst) replacing pack_bf16_rn (3 insts).
// Everything else identical to attn11.
// ---------------------------------------------------------------------------
__global__ __launch_bounds__(256) void attn13(const unsigned short* __restrict__ Qp,
                                              const unsigned short* __restrict__ Kpad,
                                              const unsigned short* __restrict__ V,
                                              const unsigned short* __restrict__ Vt,
                                              const float* __restrict__ vnorm,
                                              float* __restrict__ cosbuf) {
  __shared__ __align__(16) unsigned short Ks[64 * INNER];      // 12 KB
  __shared__ __align__(16) unsigned short VtS[INNER * 64];     // 12 KB
  __shared__ __align__(16) unsigned short Ps[4][32 * 64];      // 16 KB

  const int t = threadIdx.x;
  const int lane = t & 63, w = t >> 6;
  const int lr = lane & 15, lq = lane >> 4;
  const f32x4 z4 = {0.f, 0.f, 0.f, 0.f};

  int bx = blockIdx.x;
  const int dir = bx / 784; bx -= dir * 784;     // 784 = 49 chunks * 16 fgroups
  const int chunk = bx >> 4, fg = bx & 15;
  const int r0 = chunk * 128;
  const int qbase = dir * NSIDE;

  int goK[3], goV[3], lo[3];
#pragma unroll
  for (int j = 0; j < 3; j++) {
    int l = (w * 3 + j) * 64 + lane;
    lo[j] = l * 8;
    int rK = l / 12, scK = l - rK * 12;
    int ccK = scK - ((rK >> 1) & 7); if (ccK < 0) ccK += 12;
    goK[j] = rK * INNER + ccK * 8;
    int rV = l >> 3, scV = l & 7;
    int ccV = (scV - (rV & 7)) & 7;
    goV[j] = rV * 64 + ccV * 8;
  }
  int rdK[3], rdV[2];
#pragma unroll
  for (int ks = 0; ks < 3; ks++) {
    int sc = (ks * 4 + lq + ((lr >> 1) & 7)) % 12;
    rdK[ks] = lr * INNER + sc * 8;
  }
#pragma unroll
  for (int ks = 0; ks < 2; ks++) {
    int sc = (ks * 4 + lq + (lr & 7)) & 7;
    rdV[ks] = lr * 64 + sc * 8;
  }

  bf16x8 qf[2][3];
#pragma unroll
  for (int qt = 0; qt < 2; qt++) {
    const int qrow = qbase + r0 + w * 32 + qt * 16 + lr;
#pragma unroll
    for (int ks = 0; ks < 3; ks++)
      qf[qt][ks] = *(const bf16x8*)(Qp + (size_t)qrow * INNER + ks * 32 + lq * 8);
  }
  // ---- reference V as f32x2 pairs (for pk_fma) + 1/vnorm
  f32x2 rv2[2][6][2];
  float invvn[2];
#pragma unroll
  for (int qt = 0; qt < 2; qt++) {
    const int qrow = qbase + r0 + w * 32 + qt * 16 + lr;
    invvn[qt] = 1.f / fmaxf(vnorm[qrow], 1e-8f);
#pragma unroll
    for (int et = 0; et < 6; et++) {
      ushort4 u = *(const ushort4*)(V + (size_t)qrow * INNER + et * 16 + lq * 4);
      rv2[qt][et][0] = (f32x2){bf2f(u.x), bf2f(u.y)};
      rv2[qt][et][1] = (f32x2){bf2f(u.z), bf2f(u.w)};
    }
  }

  unsigned short* Pw = &Ps[w][0];
  const int kimg0 = (dir == 0 ? 128 : 0) + fg * 8;
  {
    const unsigned short* kg = Kpad + (size_t)kimg0 * (64 * INNER);
#pragma unroll
    for (int j = 0; j < 3; j++) gld16(kg + goK[j], Ks + lo[j]);
  }
  for (int fi = 0; fi < 8; fi++) {
    const int f = fg * 8 + fi;
    __syncthreads();   // (1) drains K[fi]; prev PV done by all waves
    {
      const unsigned short* vg = Vt + (size_t)(kimg0 + fi) * (INNER * 64);
#pragma unroll
      for (int j = 0; j < 3; j++) gld16(vg + goV[j], VtS + lo[j]);
    }
    f32x4 s4[2][4] = {{z4, z4, z4, z4}, {z4, z4, z4, z4}};
    __builtin_amdgcn_s_setprio(1);
#pragma unroll
    for (int ks = 0; ks < 3; ks++) {
#pragma unroll
      for (int kt = 0; kt < 4; kt++) {
        bf16x8 a = *(const bf16x8*)(Ks + kt * (16 * INNER) + rdK[ks]);
        s4[0][kt] = __builtin_amdgcn_mfma_f32_16x16x32_bf16(a, qf[0][ks], s4[0][kt], 0, 0, 0);
        s4[1][kt] = __builtin_amdgcn_mfma_f32_16x16x32_bf16(a, qf[1][ks], s4[1][kt], 0, 0, 0);
      }
    }
    __builtin_amdgcn_s_setprio(0);
    // ---- P[q][k] = exp2(S^T) -> Ps (XOR-chunk swizzled, wave-private)
#pragma unroll
    for (int qt = 0; qt < 2; qt++)
#pragma unroll
      for (int kt = 0; kt < 4; kt++) {
        float e0 = __builtin_exp2f(s4[qt][kt][0]);
        float e1 = __builtin_exp2f(s4[qt][kt][1]);
        float e2 = __builtin_exp2f(s4[qt][kt][2]);
        float e3 = __builtin_exp2f(s4[qt][kt][3]);
        unsigned lopk, hipk;
        asm("v_cvt_pk_bf16_f32 %0, %1, %2" : "=v"(lopk) : "v"(e0), "v"(e1));
        asm("v_cvt_pk_bf16_f32 %0, %1, %2" : "=v"(hipk) : "v"(e2), "v"(e3));
        uint2 pk = make_uint2(lopk, hipk);
        int row = qt * 16 + lr;
        int ch = (2 * kt + (lq >> 1)) ^ (row & 7);
        *(uint2*)(Pw + row * 64 + ch * 8 + (lq & 1) * 4) = pk;
      }
    __syncthreads();   // (2) drains Vt[fi]; all waves' K reads done
    if (fi < 7) {
      const unsigned short* kg = Kpad + (size_t)(kimg0 + fi + 1) * (64 * INNER);
#pragma unroll
      for (int j = 0; j < 3; j++) gld16(kg + goK[j], Ks + lo[j]);
    }
    f32x4 pv[2][6] = {{z4, z4, z4, z4, z4, z4}, {z4, z4, z4, z4, z4, z4}};
    __builtin_amdgcn_s_setprio(1);
#pragma unroll
    for (int ks = 0; ks < 2; ks++) {
      int row0 = 0 * 16 + lr, row1 = 1 * 16 + lr;
      int ch0 = ((ks * 4 + lq) ^ (row0 & 7));
      int ch1 = ((ks * 4 + lq) ^ (row1 & 7));
      bf16x8 b0 = *(const bf16x8*)(Pw + row0 * 64 + ch0 * 8);
      bf16x8 b1 = *(const bf16x8*)(Pw + row1 * 64 + ch1 * 8);
#pragma unroll
      for (int et = 0; et < 6; et++) {
        bf16x8 a = *(const bf16x8*)(VtS + et * (16 * 64) + rdV[ks]);
        pv[0][et] = __builtin_amdgcn_mfma_f32_16x16x32_bf16(a, b0, pv[0][et], 0, 0, 0);
        pv[1][et] = __builtin_amdgcn_mfma_f32_16x16x32_bf16(a, b1, pv[1][et], 0, 0, 0);
      }
    }
    __builtin_amdgcn_s_setprio(0);
    // ---- cosine epilogue per q-tile via packed f32 FMA (2-way chains)
#pragma unroll
    for (int qt = 0; qt < 2; qt++) {
      f32x2 dp = {0.f, 0.f}, np = {0.f, 0.f};
#pragma unroll
      for (int et = 0; et < 6; et++) {
        f32x2 al0 = __builtin_shufflevector(pv[qt][et], pv[qt][et], 0, 1);
        f32x2 al1 = __builtin_shufflevector(pv[qt][et], pv[qt][et], 2, 3);
        asm("v_pk_fma_f32 %0, %1, %2, %0" : "+v"(dp) : "v"(al0), "v"(rv2[qt][et][0]));
        asm("v_pk_fma_f32 %0, %1, %2, %0" : "+v"(np) : "v"(al0), "v"(al0));
        asm("v_pk_fma_f32 %0, %1, %2, %0" : "+v"(dp) : "v"(al1), "v"(rv2[qt][et][1]));
        asm("v_pk_fma_f32 %0, %1, %2, %0" : "+v"(np) : "v"(al1), "v"(al1));
      }
      float d = dp[0] + dp[1], nn = np[0] + np[1];
      d += __shfl_xor(d, 16, 64);  d += __shfl_xor(d, 32, 64);
      nn += __shfl_xor(nn, 16, 64); nn += __shfl_xor(nn, 32, 64);
      if (lane < 16) {
        float cv = d * __frsqrt_rn(fmaxf(nn, 1e-40f)) * invvn[qt];
        cosbuf[(size_t)(dir * 128 + f) * NSIDE + r0 + w * 32 + qt * 16 + lr] = cv;
      }
    }
  }
}

// ---------------------------------------------------------------------------
// reduce_out: out[bb*128+aa] = (sum_q cos0[bb][aa*49+q] + cos1[aa][bb*49+q])/49
// ---------------------------------------------------------------------------
__global__ __launch_bounds__(256) void reduce_out(const float* __restrict__ cosbuf,
                                                  float* __restrict__ out) {
  const int t = threadIdx.x, lane = t & 63, wv = t >> 6;
  const int pair = blockIdx.x * 4 + wv;
  const int bb = pair >> 7, aa = pair & 127;
  float v = 0.f;
  if (lane < S49) {
    v  = cosbuf[(size_t)bb * NSIDE + aa * S49 + lane];
    v += cosbuf[(size_t)(128 + aa) * NSIDE + bb * S49 + lane];
  }
  for (int m = 1; m < 64; m <<= 1) v += __shfl_xor(v, m, 64);
  if (lane == 0) out[pair] = v * (1.f / 49.f);
}

// ---------------------------------------------------------------------------
extern "C" void kernel_launch(void* const* d_in, const int* in_sizes, int n_in,
                              void* d_out, int out_size, void* d_ws, size_t ws_size,
                              hipStream_t stream) {
  const float* fa  = (const float*)d_in[0];
  const float* fb  = (const float*)d_in[1];
  const float* W1[3] = {(const float*)d_in[2], (const float*)d_in[4], (const float*)d_in[6]};
  const float* W2[3] = {(const float*)d_in[3], (const float*)d_in[5], (const float*)d_in[7]};
  float* out = (float*)d_out;

  unsigned short* p = (unsigned short*)d_ws;
  unsigned short* Xbf = p;                 p += (size_t)MROWS * CDIM;      // 19.3 MB
  unsigned short* W1T = p;                 p += (size_t)3 * CDIM * CDIM;   // 3.5 MB
  unsigned short* W2T = p;                 p += (size_t)3 * INNER * CDIM;  // 0.44 MB
  unsigned short* QKV = p;                 p += (size_t)3 * MROWS * INNER; // 7.2 MB
  unsigned short* Vt  = p;                 p += (size_t)256 * INNER * 64;  // 3.1 MB
  unsigned short* Kpad = p;                p += (size_t)256 * 64 * INNER;  // 3.1 MB (adjacent to Vt!)
  float* vnorm = (float*)p;                p += (size_t)MROWS * 2;         // 50 KB
  float* cosbuf = (float*)p;               p += (size_t)256 * NSIDE * 2;   // 6.4 MB
  unsigned short* H = p;                   p += (size_t)3 * MROWS * CDIM;  // 57.8 MB (batched)
  const size_t need_batched = (size_t)(p - (unsigned short*)d_ws) * 2;
  const int batched = ws_size >= need_batched;

  prep_all<<<dim3(5112), 256, 0, stream>>>(fa, fb, W1[0], W1[1], W1[2],
                                           W2[0], W2[1], W2[2],
                                           Xbf, W1T, W2T, Vt /* VtKpad span */);
  if (batched) {
    gemm1_8p<<<dim3(CDIM / 256, MROWS / 256, 3), 512, 0, stream>>>(Xbf, W1T, H, 0, 1);
    gemm2b5<<<dim3(MROWS / 64, 3), 512, 0, stream>>>(H, W2T, QKV, Kpad, Vt, vnorm, 0, 1);
  } else {
    for (int wdx = 0; wdx < 3; wdx++) {
      gemm1_8p<<<dim3(CDIM / 256, MROWS / 256, 1), 512, 0, stream>>>(Xbf, W1T, H, wdx, 0);
      gemm2b5<<<dim3(MROWS / 64, 1), 512, 0, stream>>>(H, W2T, QKV, Kpad, Vt, vnorm, wdx, 0);
    }
  }
  attn13<<<dim3(2 * 784), 256, 0, stream>>>(
      QKV, Kpad, QKV + (size_t)2 * MROWS * INNER, Vt, vnorm, cosbuf);
  reduce_out<<<dim3(4096), 256, 0, stream>>>(cosbuf, out);
}